// Round 1
// 1112.596 us; speedup vs baseline: 1.1124x; 1.1124x over previous
//
#include <hip/hip_runtime.h>
#include <stdint.h>

#define NV 20000
#define NE 100000
#define NK 8
#define FIN 1024
#define FOUT 512
#define FTOT 1120
#define KP 1152           // K padded to 18*64
#define MP 20096          // M padded to 157*128
#define CAP 4096
#define ROUNDS 13
#define NB 32             // edge-chunk blocks per filtration in k_candA
#define CHUNK (NE / NB)
#define LDA 72            // LDS row stride (bf16 elems): 64 + 8 pad

typedef unsigned int u32;
typedef unsigned long long u64;
typedef unsigned short u16;
typedef __attribute__((ext_vector_type(8))) short bf16x8;
typedef __attribute__((ext_vector_type(4))) float f32x4;

// float -> order-preserving unsigned bits, and inverse
__device__ __forceinline__ u32 sb(float x) {
    u32 u = __float_as_uint(x);
    return u ^ ((u & 0x80000000u) ? 0xFFFFFFFFu : 0x80000000u);
}
__device__ __forceinline__ float isb(u32 s) {
    u32 u = (s & 0x80000000u) ? (s ^ 0x80000000u) : ~s;
    return __uint_as_float(u);
}
// float -> bf16 (RNE)
__device__ __forceinline__ u16 f2bf(float f) {
    u32 u = __float_as_uint(f);
    return (u16)((u + 0x7FFFu + ((u >> 16) & 1u)) >> 16);
}

// ---------------- GEMM1: f[k][v] = x[v] . filt_w[k] + filt_b[k] (fp32 exact path)
__global__ void k_f(const float* __restrict__ x, const float* __restrict__ fw,
                    const float* __restrict__ fb, float* __restrict__ f) {
    __shared__ float w[NK * FIN];  // 32 KB
    for (int i = threadIdx.x; i < NK * FIN; i += 256) w[i] = fw[i];
    __syncthreads();
    int wave = threadIdx.x >> 6, lane = threadIdx.x & 63;
    int v = blockIdx.x * 4 + wave;  // 5000 * 4 waves = 20000 exact
    float acc[NK];
#pragma unroll
    for (int k = 0; k < NK; k++) acc[k] = 0.f;
    const float* xr = x + (size_t)v * FIN;
    for (int c = 0; c < FIN / 64; c++) {
        int i = c * 64 + lane;
        float xv = xr[i];
#pragma unroll
        for (int k = 0; k < NK; k++) acc[k] = fmaf(xv, w[k * FIN + i], acc[k]);
    }
#pragma unroll
    for (int off = 32; off >= 1; off >>= 1)
#pragma unroll
        for (int k = 0; k < NK; k++) acc[k] += __shfl_xor(acc[k], off, 64);
    if (lane < NK) f[lane * NV + v] = acc[lane] + fb[lane];
}

// ---------------- init: comp identity, cand = ~0, counters = 0 ----------------
__global__ void k_init(u32* __restrict__ comp, u64* __restrict__ cand, u32* cnts) {
    int t = blockIdx.x * 256 + threadIdx.x;  // 32768
    comp[t] = (u32)(t % CAP);
    cand[t] = ~0ull;
    if (t < 32) cnts[t] = 0;
}

// ---------------- cast x into fused bf16 A (cols 0..1023; zero pads) ----------
__global__ void k_castx(const float* __restrict__ x, u16* __restrict__ A) {
    int t = blockIdx.x * 256 + threadIdx.x;  // MP * 144
    if (t >= MP * 144) return;
    int v = t / 144, c = (t % 144) * 8;
    u32 pk[4];
    if (v < NV && c < FIN) {
        const float* xr = x + (size_t)v * FIN + c;
#pragma unroll
        for (int j = 0; j < 4; j++)
            pk[j] = (u32)f2bf(xr[2 * j]) | ((u32)f2bf(xr[2 * j + 1]) << 16);
    } else {
#pragma unroll
        for (int j = 0; j < 4; j++) pk[j] = 0u;
    }
    *(uint4*)(A + (size_t)v * KP + c) = make_uint4(pk[0], pk[1], pk[2], pk[3]);
}

// ---------------- cast out_w into bf16 W [512][1152] --------------------------
__global__ void k_castw(const float* __restrict__ ow, u16* __restrict__ W) {
    int t = blockIdx.x * 256 + threadIdx.x;  // 512*144
    if (t >= FOUT * 144) return;
    int n = t / 144, c = (t % 144) * 8;
    u32 pk[4];
    if (c < FTOT) {
        const float* wr = ow + (size_t)n * FTOT + c;
#pragma unroll
        for (int j = 0; j < 4; j++)
            pk[j] = (u32)f2bf(wr[2 * j]) | ((u32)f2bf(wr[2 * j + 1]) << 16);
    } else {
#pragma unroll
        for (int j = 0; j < 4; j++) pk[j] = 0u;
    }
    *(uint4*)(W + (size_t)n * KP + c) = make_uint4(pk[0], pk[1], pk[2], pk[3]);
}

// ---------------- descent pointers ----------------
__global__ void k_initdesc(const float* __restrict__ f, u64* __restrict__ cd) {
    int t = blockIdx.x * 256 + threadIdx.x;  // 160000
    u32 v = (u32)(t % NV);
    cd[t] = ((u64)sb(f[t]) << 32) | v;
}

__global__ void k_descedge(const int* __restrict__ ei, const float* __restrict__ f,
                           u64* __restrict__ cd) {
    int t = blockIdx.x * 256 + threadIdx.x;  // 800000
    int k = t / NE, e = t % NE;
    int a = ei[e], b = ei[NE + e];
    if (a == b) return;
    float fa = f[k * NV + a], fb2 = f[k * NV + b];
    int d, l; float fl;
    if (fa >= fb2) { d = a; l = b; fl = fb2; } else { d = b; l = a; fl = fa; }
    u64 key = ((u64)sb(fl) << 32) | (u32)l;
    atomicMin(&cd[k * NV + d], key);
}

__global__ void k_basin(const u64* __restrict__ cd, u32* __restrict__ basin) {
    int t = blockIdx.x * 256 + threadIdx.x;
    int k = t / NV;
    u32 m = (u32)(t % NV);
    const u64* c = cd + (size_t)k * NV;
    while (true) { u32 n = (u32)c[m]; if (n == m) break; m = n; }
    basin[t] = m;
}

__global__ void k_minima(const u64* __restrict__ cd, u32* nmin,
                         u32* __restrict__ mlist, u32* __restrict__ dense) {
    int t = blockIdx.x * 256 + threadIdx.x;
    int k = t / NV; u32 v = (u32)(t % NV);
    if ((u32)cd[t] == v) {
        u32 i = atomicAdd(&nmin[k], 1u);
        if (i < CAP) { mlist[k * CAP + i] = v; dense[t] = i; }
    }
}

__global__ void k_edgeprep(const int* __restrict__ ei, const float* __restrict__ f,
                           const u32* __restrict__ basin, const u32* __restrict__ dense,
                           u64* __restrict__ wkey, u32* __restrict__ ep) {
    int t = blockIdx.x * 256 + threadIdx.x;  // 800000
    int k = t / NE, e = t % NE;
    int a = ei[e], b = ei[NE + e];
    if (a == b) { ep[t] = 0xFFFFFFFFu; return; }
    float fa = f[k * NV + a], fb2 = f[k * NV + b];
    float w = (fa >= fb2) ? fa : fb2;
    wkey[t] = ((u64)sb(w) << 32) | (u32)e;
    u32 ba = basin[k * NV + a], bb = basin[k * NV + b];
    if (ba == bb) { ep[t] = 0xFFFFFFFFu; return; }
    u32 da = dense[k * NV + ba], db = dense[k * NV + bb];
    ep[t] = (da << 16) | db;
}

// ---------------- Boruvka phase A: per-block LDS cand, sparse flush ------------
__device__ __forceinline__ u32 rootofs(const u32* c, u32 i) {
    while (true) { u32 p = c[i]; if (p == i) return i; i = p; }
}

__global__ void k_candA(const u32* __restrict__ ep, const u64* __restrict__ wkey,
                        const u32* __restrict__ comp_g, u64* __restrict__ cand_g,
                        const u32* __restrict__ done) {
    __shared__ u32 scomp[CAP];  // 16 KB
    __shared__ u64 scand[CAP];  // 32 KB
    int k = blockIdx.y, b = blockIdx.x;
    if (done[k]) return;  // converged: provably no more cross-component edges
    for (int i = threadIdx.x; i < CAP; i += 256) {
        scomp[i] = comp_g[k * CAP + i];
        scand[i] = ~0ull;
    }
    __syncthreads();
    int e0 = b * CHUNK;
    const u32* epk = ep + (size_t)k * NE;
    const u64* wkk = wkey + (size_t)k * NE;
    for (int e = e0 + threadIdx.x; e < e0 + CHUNK; e += 256) {
        u32 p32 = epk[e];
        if (p32 == 0xFFFFFFFFu) continue;
        u32 A = rootofs(scomp, p32 >> 16), B = rootofs(scomp, p32 & 0xFFFFu);
        if (A == B) continue;
        u64 w = wkk[e];
        atomicMin(&scand[A], w);
        atomicMin(&scand[B], w);
    }
    __syncthreads();
    u64* cnd = cand_g + (size_t)k * CAP;
    for (int i = threadIdx.x; i < CAP; i += 256) {
        u64 v = scand[i];
        if (v != ~0ull) atomicMin(&cnd[i], v);
    }
}

// ---------------- Boruvka phase B: hook + apply + compress + clear (fused) -----
__global__ void k_round(u64* __restrict__ cand_g, const u32* __restrict__ ep,
                        u32* __restrict__ comp_g, u32* mstcnt,
                        u64* __restrict__ mkey, u32* __restrict__ mpay,
                        u32* __restrict__ done) {
    __shared__ u64 scand[CAP];  // 32 KB
    __shared__ u32 scomp[CAP];  // 16 KB
    __shared__ u32 shk[CAP];    // 16 KB
    __shared__ u32 nmerge;
    int k = blockIdx.x;
    if (done[k]) return;
    if (threadIdx.x == 0) nmerge = 0;
    for (int i = threadIdx.x; i < CAP; i += 1024) {
        scand[i] = cand_g[k * CAP + i];
        scomp[i] = comp_g[k * CAP + i];
    }
    __syncthreads();
    for (int i = threadIdx.x; i < CAP; i += 1024) {
        u64 cc = scand[i];
        if (cc == ~0ull) { shk[i] = (u32)i; continue; }
        u32 e = (u32)cc;
        u32 p32 = ep[(size_t)k * NE + e];
        u32 A = rootofs(scomp, p32 >> 16), B = rootofs(scomp, p32 & 0xFFFFu);
        shk[i] = (A == (u32)i) ? B : A;
    }
    __syncthreads();
    for (int i = threadIdx.x; i < CAP; i += 1024) {
        u32 o = shk[i];
        if (o == (u32)i) continue;
        bool mutual = (shk[o] == (u32)i);
        if (mutual && (u32)i < o) continue;
        scomp[i] = o;
        u64 cc = scand[i];
        u32 e = (u32)cc;
        u32 j = atomicAdd(&mstcnt[k], 1u);
        atomicAdd(&nmerge, 1u);
        if (j < CAP) { mkey[k * CAP + j] = cc; mpay[k * CAP + j] = ep[(size_t)k * NE + e]; }
    }
    __syncthreads();
    for (int i = threadIdx.x; i < CAP; i += 1024) scomp[i] = rootofs(scomp, i);
    __syncthreads();
    for (int i = threadIdx.x; i < CAP; i += 1024) {
        comp_g[k * CAP + i] = scomp[i];
        cand_g[k * CAP + i] = ~0ull;
    }
    if (threadIdx.x == 0 && nmerge == 0) done[k] = 1;  // zero merges => terminal
}

// ---------------- sort MSF edges per filtration (bitonic in LDS) ---------------
__global__ void k_sort(const u32* mstcnt, u64* __restrict__ mkey, u32* __restrict__ mpay) {
    __shared__ u64 skey[CAP];   // 32 KB
    __shared__ u32 spay[CAP];   // 16 KB
    int k = blockIdx.x;
    u32 cnt = mstcnt[k]; if (cnt > CAP) cnt = CAP;
    int n2 = 64; while (n2 < (int)cnt) n2 <<= 1;  // sort only next-pow2 >= cnt
    for (int i = threadIdx.x; i < CAP; i += 256) {
        skey[i] = (i < (int)cnt) ? mkey[k * CAP + i] : ~0ull;
        spay[i] = (i < (int)cnt) ? mpay[k * CAP + i] : 0u;
    }
    __syncthreads();
    for (int sz = 2; sz <= n2; sz <<= 1) {
        for (int st = sz >> 1; st >= 1; st >>= 1) {
            for (int i = threadIdx.x; i < n2; i += 256) {
                int j = i ^ st;
                if (j > i) {
                    bool up = ((i & sz) == 0);
                    u64 a = skey[i], b = skey[j];
                    bool sw = up ? (a > b) : (a < b);
                    if (sw) {
                        skey[i] = b; skey[j] = a;
                        u32 tp = spay[i]; spay[i] = spay[j]; spay[j] = tp;
                    }
                }
            }
            __syncthreads();
        }
    }
    for (int i = threadIdx.x; i < CAP; i += 256) {
        mkey[k * CAP + i] = skey[i];
        mpay[k * CAP + i] = spay[i];
    }
}

// ---------------- dval default: death = birth ---------------------------------
__global__ void k_dvinit(const float* __restrict__ f, float* __restrict__ dval) {
    int t = blockIdx.x * 256 + threadIdx.x;  // 160000
    dval[t] = f[t];
}

// ---- elder-rule pairing: wave-parallel speculative Kruskal windows (64 edges) --
// par[i]: parent (dense id). val[i]: f bits while root; death sortbits once dead.
// One wave per filtration. Sequential semantics preserved exactly.
// Gauss-Seidel single-pass resolution: merge chains strictly ascend in lane
// index (an edge's surviving root is alive through its step, so it can only be
// killed by a LATER edge). Hence at scan step jj, lane jj has already applied
// all remaps from steps < jj and its current tentative merge is FINAL when
// broadcast — one 63-step pass replaces the Jacobi fixed-point + ballot.
__global__ __launch_bounds__(64) void k_pairw(
    const u32* nmin, const u32* __restrict__ mlist, const u32* mstcnt,
    const u64* __restrict__ mkey, const u32* __restrict__ mpay,
    const float* __restrict__ f, float* __restrict__ dval) {
    __shared__ u32 par[CAP];  // 16 KB
    __shared__ u32 val[CAP];  // 16 KB
    int k = blockIdx.x;
    int lane = threadIdx.x;
    u32 nm = nmin[k]; if (nm > CAP) nm = CAP;
    u32 cnt = mstcnt[k]; if (cnt > CAP) cnt = CAP;
    for (int i = lane; i < CAP; i += 64) {
        par[i] = (u32)i;
        val[i] = (i < (int)nm) ? __float_as_uint(f[k * NV + mlist[k * CAP + i]]) : 0u;
    }
    __syncthreads();
    u32 nw = (cnt + 63) >> 6;
    for (u32 w = 0; w < nw; w++) {
        u32 j = w * 64 + (u32)lane;
        bool valid = j < cnt;
        u32 wb = 0, la = 0, lb = 0;
        if (valid) {
            u64 key = mkey[(size_t)k * CAP + j];
            wb = (u32)(key >> 32);
            u32 pay = mpay[(size_t)k * CAP + j];
            la = pay >> 16; lb = pay & 0xFFFFu;
        }
        // phase A: pre-window roots with path halving (parallel across lanes)
        u32 rA = la, rB = lb;
        if (valid) {
            while (true) { u32 p = par[rA]; if (p == rA) break;
                           u32 g = par[p]; par[rA] = g; rA = (g == p) ? p : g; }
            while (true) { u32 p = par[rB]; if (p == rB) break;
                           u32 g = par[p]; par[rB] = g; rB = (g == p) ? p : g; }
        }
        u32 cA = rA, cvA = valid ? val[rA] : 0u;
        u32 cB = rB, cvB = valid ? val[rB] : 0u;
        // initial tentative merge (final for lane 0)
        u32 t_fy = 0xFFFFFFFFu, t_fo = 0u, t_fvo = 0u;
        if (valid) {
            if (__uint_as_float(cvA) <= __uint_as_float(cvB)) { t_fo = cA; t_fvo = cvA; t_fy = cB; }
            else                                              { t_fo = cB; t_fvo = cvB; t_fy = cA; }
        }
        // phase B: single Gauss-Seidel ascending pass (lane jj final at step jj)
#pragma unroll
        for (int jj = 0; jj < 63; jj++) {
            u32 oy = __shfl(t_fy, jj);
            u32 oo = __shfl(t_fo, jj);
            u32 ov = __shfl(t_fvo, jj);
            bool app = (jj < lane) && valid;
            bool mA = app && (cA == oy);
            bool mB = app && (cB == oy);
            if (mA) { cA = oo; cvA = ov; }
            if (mB) { cB = oo; cvB = ov; }
            if (mA || mB) {
                if (__uint_as_float(cvA) <= __uint_as_float(cvB)) { t_fo = cA; t_fvo = cvA; t_fy = cB; }
                else                                              { t_fo = cB; t_fvo = cvB; t_fy = cA; }
            }
        }
        // commit: distinct t_fy across lanes; chains remain chaseable
        if (valid) { par[t_fy] = t_fo; val[t_fy] = wb; }
        __syncthreads();
    }
    // extraction: dead minima get death value from val slot
    for (int i = lane; i < (int)nm; i += 64) {
        if (par[i] != (u32)i)
            dval[k * NV + mlist[k * CAP + i]] = isb(val[i]);
    }
}

// ---------------- coordinate features -> bf16 directly into fused A ------------
__global__ void k_coordb(const float* __restrict__ f, const float* __restrict__ dval,
                         const float* __restrict__ tri_t, const float* __restrict__ gmu,
                         const float* __restrict__ gsig, const float* __restrict__ lw,
                         const float* __restrict__ rc, const float* __restrict__ rr,
                         u16* __restrict__ A) {
    int t = blockIdx.x * 256 + threadIdx.x;  // 160000
    int k = t / NV, v = t % NV;
    float b = f[t], d = dval[t];
    float o[12];
    float s = gsig[0];
    float inv2s2 = 1.0f / (2.0f * s * s);
    float r = fabsf(rr[0]);
#pragma unroll
    for (int j = 0; j < 3; j++) {
        float tri = d - fabsf(tri_t[j] - b);
        o[j] = tri > 0.f ? tri : 0.f;
        float dx = b - gmu[2 * j], dy = d - gmu[2 * j + 1];
        o[3 + j] = expf(-(dx * dx + dy * dy) * inv2s2);
        o[6 + j] = b * lw[2 * j] + d * lw[2 * j + 1];
        float q = fabsf(b - rc[2 * j]) + fabsf(d - rc[2 * j + 1]);
        o[9 + j] = 1.0f / (1.0f + q) - 1.0f / (1.0f + fabsf(r - q));
    }
    u16* dst = A + (size_t)v * KP + FIN + k * 12;  // 4B-aligned (2048+24k bytes)
    u32* d32 = (u32*)dst;
#pragma unroll
    for (int j = 0; j < 6; j++)
        d32[j] = (u32)f2bf(o[2 * j]) | ((u32)f2bf(o[2 * j + 1]) << 16);
}

// ---------------- GEMM2: out = A(bf16) @ W(bf16)^T + bias, MFMA ----------------
__global__ __launch_bounds__(256, 2) void k_gemm2(
    const u16* __restrict__ A, const u16* __restrict__ W,
    const float* __restrict__ bias, float* __restrict__ out) {
    __shared__ u16 As[128 * LDA];  // 18 KB
    __shared__ u16 Bs[128 * LDA];  // 18 KB
    int n0 = blockIdx.x * 128, m0 = blockIdx.y * 128;
    int t = threadIdx.x;
    int wave = t >> 6, lane = t & 63;
    int wm = (wave >> 1) * 64, wn = (wave & 1) * 64;
    int lrow = lane & 15, lq = lane >> 4;
    f32x4 acc[4][4];
#pragma unroll
    for (int i = 0; i < 4; i++)
#pragma unroll
        for (int j = 0; j < 4; j++) acc[i][j] = (f32x4){0.f, 0.f, 0.f, 0.f};

    int rowc[4], colc[4];
    uint4 av[4], bv[4];
#pragma unroll
    for (int i = 0; i < 4; i++) {
        int c = i * 256 + t;            // 0..1023 chunks of 8 bf16
        rowc[i] = c >> 3;
        colc[i] = (c & 7) * 8;
        av[i] = *(const uint4*)(A + (size_t)(m0 + rowc[i]) * KP + colc[i]);
        bv[i] = *(const uint4*)(W + (size_t)(n0 + rowc[i]) * KP + colc[i]);
    }
#pragma unroll 1
    for (int step = 0; step < KP / 64; step++) {
        __syncthreads();
#pragma unroll
        for (int i = 0; i < 4; i++) {
            *(uint4*)(As + rowc[i] * LDA + colc[i]) = av[i];
            *(uint4*)(Bs + rowc[i] * LDA + colc[i]) = bv[i];
        }
        __syncthreads();
        int k0n = (step + 1 < KP / 64) ? (step + 1) * 64 : 0;  // prefetch (clamped)
#pragma unroll
        for (int i = 0; i < 4; i++) {
            av[i] = *(const uint4*)(A + (size_t)(m0 + rowc[i]) * KP + k0n + colc[i]);
            bv[i] = *(const uint4*)(W + (size_t)(n0 + rowc[i]) * KP + k0n + colc[i]);
        }
#pragma unroll
        for (int kh = 0; kh < 2; kh++) {
            int kk = kh * 32 + lq * 8;
            bf16x8 af[4], bfr[4];
#pragma unroll
            for (int mt = 0; mt < 4; mt++)
                af[mt] = *(const bf16x8*)(As + (wm + mt * 16 + lrow) * LDA + kk);
#pragma unroll
            for (int nt = 0; nt < 4; nt++)
                bfr[nt] = *(const bf16x8*)(Bs + (wn + nt * 16 + lrow) * LDA + kk);
#pragma unroll
            for (int mt = 0; mt < 4; mt++)
#pragma unroll
                for (int nt = 0; nt < 4; nt++)
                    acc[mt][nt] = __builtin_amdgcn_mfma_f32_16x16x32_bf16(
                        af[mt], bfr[nt], acc[mt][nt], 0, 0, 0);
        }
    }
    // epilogue: row = (lane>>4)*4 + reg, col = lane&15  [verified C/D layout]
#pragma unroll
    for (int nt = 0; nt < 4; nt++) {
        int o = n0 + wn + nt * 16 + lrow;
        float bz = bias[o];
#pragma unroll
        for (int mt = 0; mt < 4; mt++) {
#pragma unroll
            for (int i = 0; i < 4; i++) {
                int v = m0 + wm + mt * 16 + lq * 4 + i;
                if (v < NV) out[(size_t)v * FOUT + o] = acc[mt][nt][i] + bz;
            }
        }
    }
}

extern "C" void kernel_launch(void* const* d_in, const int* in_sizes, int n_in,
                              void* d_out, int out_size, void* d_ws, size_t ws_size,
                              hipStream_t stream) {
    const float* x     = (const float*)d_in[0];
    const int*   ei    = (const int*)d_in[1];
    const float* fw    = (const float*)d_in[2];
    const float* fbv   = (const float*)d_in[3];
    const float* tri_t = (const float*)d_in[4];
    const float* gmu   = (const float*)d_in[5];
    const float* gsig  = (const float*)d_in[6];
    const float* lw    = (const float*)d_in[7];
    const float* rc    = (const float*)d_in[8];
    const float* rr    = (const float*)d_in[9];
    const float* ow    = (const float*)d_in[10];
    const float* ob    = (const float*)d_in[11];
    float* out = (float*)d_out;

    char* p = (char*)d_ws;
    auto alloc = [&](size_t bytes) -> void* {
        void* q = (void*)p;
        p += (bytes + 255) & ~(size_t)255;
        return q;
    };
    float* f     = (float*)alloc((size_t)NK * NV * 4);
    u64*   cd    = (u64*)  alloc((size_t)NK * NV * 8);
    u32*   basin = (u32*)  alloc((size_t)NK * NV * 4);
    u32*   dense = (u32*)  alloc((size_t)NK * NV * 4);
    u32*   mlist = (u32*)  alloc((size_t)NK * CAP * 4);
    u32*   cnts  = (u32*)  alloc(64 * 4);
    u64*   wkey  = (u64*)  alloc((size_t)NK * NE * 8);
    u32*   ep    = (u32*)  alloc((size_t)NK * NE * 4);
    u32*   comp  = (u32*)  alloc((size_t)NK * CAP * 4);
    u64*   cand  = (u64*)  alloc((size_t)NK * CAP * 8);
    u64*   mkey  = (u64*)  alloc((size_t)NK * CAP * 8);
    u32*   mpay  = (u32*)  alloc((size_t)NK * CAP * 4);
    float* dval  = (float*)alloc((size_t)NK * NV * 4);
    u16*   Ab    = (u16*)  alloc((size_t)MP * KP * 2);   // 46.3 MB fused [x|coord|pad]
    u16*   Wb    = (u16*)  alloc((size_t)FOUT * KP * 2); // 1.2 MB
    u32* nmin = cnts; u32* mstcnt = cnts + 8; u32* done = cnts + 16;

    k_init<<<128, 256, 0, stream>>>(comp, cand, cnts);
    k_f<<<5000, 256, 0, stream>>>(x, fw, fbv, f);
    k_dvinit<<<625, 256, 0, stream>>>(f, dval);
    k_castx<<<(MP * 144 + 255) / 256, 256, 0, stream>>>(x, Ab);
    k_castw<<<(FOUT * 144 + 255) / 256, 256, 0, stream>>>(ow, Wb);
    k_initdesc<<<625, 256, 0, stream>>>(f, cd);
    k_descedge<<<3125, 256, 0, stream>>>(ei, f, cd);
    k_basin<<<625, 256, 0, stream>>>(cd, basin);
    k_minima<<<625, 256, 0, stream>>>(cd, nmin, mlist, dense);
    k_edgeprep<<<3125, 256, 0, stream>>>(ei, f, basin, dense, wkey, ep);
    for (int r = 0; r < ROUNDS; r++) {
        k_candA<<<dim3(NB, NK), 256, 0, stream>>>(ep, wkey, comp, cand, done);
        k_round<<<NK, 1024, 0, stream>>>(cand, ep, comp, mstcnt, mkey, mpay, done);
    }
    k_sort<<<8, 256, 0, stream>>>(mstcnt, mkey, mpay);
    k_pairw<<<8, 64, 0, stream>>>(nmin, mlist, mstcnt, mkey, mpay, f, dval);
    k_coordb<<<625, 256, 0, stream>>>(f, dval, tri_t, gmu, gsig, lw, rc, rr, Ab);
    k_gemm2<<<dim3(4, 157), 256, 0, stream>>>(Ab, Wb, ob, out);
}

// Round 2
// 1108.651 us; speedup vs baseline: 1.1164x; 1.0036x over previous
//
#include <hip/hip_runtime.h>
#include <stdint.h>

#define NV 20000
#define NE 100000
#define NK 8
#define FIN 1024
#define FOUT 512
#define FTOT 1120
#define KP 1152           // K padded to 18*64
#define MP 20096          // M padded to 157*128
#define CAP 4096
#define ROUNDS 13
#define NB 32             // edge-chunk blocks per filtration in k_candA
#define CHUNK (NE / NB)
#define LDA 72            // LDS row stride (bf16 elems): 64 + 8 pad

typedef unsigned int u32;
typedef unsigned long long u64;
typedef unsigned short u16;
typedef __attribute__((ext_vector_type(8))) short bf16x8;
typedef __attribute__((ext_vector_type(4))) float f32x4;

// float -> order-preserving unsigned bits, and inverse
__device__ __forceinline__ u32 sb(float x) {
    u32 u = __float_as_uint(x);
    return u ^ ((u & 0x80000000u) ? 0xFFFFFFFFu : 0x80000000u);
}
__device__ __forceinline__ float isb(u32 s) {
    u32 u = (s & 0x80000000u) ? (s ^ 0x80000000u) : ~s;
    return __uint_as_float(u);
}
// float -> bf16 (RNE)
__device__ __forceinline__ u16 f2bf(float f) {
    u32 u = __float_as_uint(f);
    return (u16)((u + 0x7FFFu + ((u >> 16) & 1u)) >> 16);
}

// ---- fused GEMM1 + bf16 cast of x into A ------------------------------------
// Each wave owns one row v: stages it in LDS (float4), computes the 8 dots with
// the SAME summation order as before (stride-64 over c-chunks -> bit-identical
// f), then emits the bf16 row into A (cols 0..1023 data, 1024..1151 zeros).
// Saves a full 82 MB re-read of x vs separate k_castx.
__global__ __launch_bounds__(256) void k_fx(
    const float* __restrict__ x, const float* __restrict__ fw,
    const float* __restrict__ fb, float* __restrict__ f, u16* __restrict__ A) {
    __shared__ float w[NK * FIN];   // 32 KB
    __shared__ float xs[4][FIN];    // 16 KB
    for (int i = threadIdx.x; i < NK * FIN; i += 256) w[i] = fw[i];
    __syncthreads();
    int wave = threadIdx.x >> 6, lane = threadIdx.x & 63;
    int v = blockIdx.x * 4 + wave;  // 5024 * 4 = 20096 = MP
    float4* xd = (float4*)xs[wave];
    if (v < NV) {
        const float4* xr4 = (const float4*)(x + (size_t)v * FIN);
        for (int i = lane; i < FIN / 4; i += 64) xd[i] = xr4[i];
    } else {
        for (int i = lane; i < FIN / 4; i += 64) xd[i] = make_float4(0.f, 0.f, 0.f, 0.f);
    }
    // same-wave produce->consume: no barrier needed (lgkmcnt ordering)
    float acc[NK];
#pragma unroll
    for (int k = 0; k < NK; k++) acc[k] = 0.f;
    for (int c = 0; c < FIN / 64; c++) {
        int i = c * 64 + lane;
        float xv = xs[wave][i];
#pragma unroll
        for (int k = 0; k < NK; k++) acc[k] = fmaf(xv, w[k * FIN + i], acc[k]);
    }
#pragma unroll
    for (int off = 32; off >= 1; off >>= 1)
#pragma unroll
        for (int k = 0; k < NK; k++) acc[k] += __shfl_xor(acc[k], off, 64);
    if (v < NV && lane < NK) f[lane * NV + v] = acc[lane] + fb[lane];
    // bf16 emit: 144 chunks of 8 cols (1152 total), zeros beyond FIN
    for (int cc = lane; cc < 144; cc += 64) {
        int c0 = cc * 8;
        u32 pk[4];
        if (c0 < FIN) {
#pragma unroll
            for (int j = 0; j < 4; j++)
                pk[j] = (u32)f2bf(xs[wave][c0 + 2 * j]) |
                        ((u32)f2bf(xs[wave][c0 + 2 * j + 1]) << 16);
        } else {
#pragma unroll
            for (int j = 0; j < 4; j++) pk[j] = 0u;
        }
        *(uint4*)(A + (size_t)v * KP + c0) = make_uint4(pk[0], pk[1], pk[2], pk[3]);
    }
}

// ---------------- init: comp identity, cand = ~0, counters = 0 ----------------
__global__ void k_init(u32* __restrict__ comp, u64* __restrict__ cand, u32* cnts) {
    int t = blockIdx.x * 256 + threadIdx.x;  // 32768
    comp[t] = (u32)(t % CAP);
    cand[t] = ~0ull;
    if (t < 32) cnts[t] = 0;
}

// ---------------- cast out_w into bf16 W [512][1152] --------------------------
__global__ void k_castw(const float* __restrict__ ow, u16* __restrict__ W) {
    int t = blockIdx.x * 256 + threadIdx.x;  // 512*144
    if (t >= FOUT * 144) return;
    int n = t / 144, c = (t % 144) * 8;
    u32 pk[4];
    if (c < FTOT) {
        const float* wr = ow + (size_t)n * FTOT + c;
#pragma unroll
        for (int j = 0; j < 4; j++)
            pk[j] = (u32)f2bf(wr[2 * j]) | ((u32)f2bf(wr[2 * j + 1]) << 16);
    } else {
#pragma unroll
        for (int j = 0; j < 4; j++) pk[j] = 0u;
    }
    *(uint4*)(W + (size_t)n * KP + c) = make_uint4(pk[0], pk[1], pk[2], pk[3]);
}

// ---------------- descent pointers (+ dval default: death = birth) ------------
__global__ void k_initdesc(const float* __restrict__ f, u64* __restrict__ cd,
                           float* __restrict__ dval) {
    int t = blockIdx.x * 256 + threadIdx.x;  // 160000
    u32 v = (u32)(t % NV);
    float fv = f[t];
    cd[t] = ((u64)sb(fv) << 32) | v;
    dval[t] = fv;
}

__global__ void k_descedge(const int* __restrict__ ei, const float* __restrict__ f,
                           u64* __restrict__ cd) {
    int t = blockIdx.x * 256 + threadIdx.x;  // 800000
    int k = t / NE, e = t % NE;
    int a = ei[e], b = ei[NE + e];
    if (a == b) return;
    float fa = f[k * NV + a], fb2 = f[k * NV + b];
    int d, l; float fl;
    if (fa >= fb2) { d = a; l = b; fl = fb2; } else { d = b; l = a; fl = fa; }
    u64 key = ((u64)sb(fl) << 32) | (u32)l;
    atomicMin(&cd[k * NV + d], key);
}

// ---------------- basin chase + minima detection (fused) ----------------------
__global__ void k_basmin(const u64* __restrict__ cd, u32* __restrict__ basin,
                         u32* nmin, u32* __restrict__ mlist, u32* __restrict__ dense) {
    int t = blockIdx.x * 256 + threadIdx.x;
    int k = t / NV; u32 v = (u32)(t % NV);
    const u64* c = cd + (size_t)k * NV;
    u32 m = (u32)c[v];
    if (m == v) {
        basin[t] = v;
        u32 i = atomicAdd(&nmin[k], 1u);
        if (i < CAP) { mlist[k * CAP + i] = v; dense[t] = i; }
    } else {
        while (true) { u32 n = (u32)c[m]; if (n == m) break; m = n; }
        basin[t] = m;
    }
}

__global__ void k_edgeprep(const int* __restrict__ ei, const float* __restrict__ f,
                           const u32* __restrict__ basin, const u32* __restrict__ dense,
                           u64* __restrict__ wkey, u32* __restrict__ ep) {
    int t = blockIdx.x * 256 + threadIdx.x;  // 800000
    int k = t / NE, e = t % NE;
    int a = ei[e], b = ei[NE + e];
    if (a == b) { ep[t] = 0xFFFFFFFFu; return; }
    float fa = f[k * NV + a], fb2 = f[k * NV + b];
    float w = (fa >= fb2) ? fa : fb2;
    wkey[t] = ((u64)sb(w) << 32) | (u32)e;
    u32 ba = basin[k * NV + a], bb = basin[k * NV + b];
    if (ba == bb) { ep[t] = 0xFFFFFFFFu; return; }
    u32 da = dense[k * NV + ba], db = dense[k * NV + bb];
    ep[t] = (da << 16) | db;
}

// ---------------- Boruvka phase A: per-block LDS cand, sparse flush ------------
__device__ __forceinline__ u32 rootofs(const u32* c, u32 i) {
    while (true) { u32 p = c[i]; if (p == i) return i; i = p; }
}

__global__ void k_candA(const u32* __restrict__ ep, const u64* __restrict__ wkey,
                        const u32* __restrict__ comp_g, u64* __restrict__ cand_g,
                        const u32* __restrict__ done) {
    __shared__ u32 scomp[CAP];  // 16 KB
    __shared__ u64 scand[CAP];  // 32 KB
    int k = blockIdx.y, b = blockIdx.x;
    if (done[k]) return;  // converged: provably no more cross-component edges
    for (int i = threadIdx.x; i < CAP; i += 256) {
        scomp[i] = comp_g[k * CAP + i];
        scand[i] = ~0ull;
    }
    __syncthreads();
    int e0 = b * CHUNK;
    const u32* epk = ep + (size_t)k * NE;
    const u64* wkk = wkey + (size_t)k * NE;
    for (int e = e0 + threadIdx.x; e < e0 + CHUNK; e += 256) {
        u32 p32 = epk[e];
        if (p32 == 0xFFFFFFFFu) continue;
        u32 A = rootofs(scomp, p32 >> 16), B = rootofs(scomp, p32 & 0xFFFFu);
        if (A == B) continue;
        u64 w = wkk[e];
        atomicMin(&scand[A], w);
        atomicMin(&scand[B], w);
    }
    __syncthreads();
    u64* cnd = cand_g + (size_t)k * CAP;
    for (int i = threadIdx.x; i < CAP; i += 256) {
        u64 v = scand[i];
        if (v != ~0ull) atomicMin(&cnd[i], v);
    }
}

// ---------------- Boruvka phase B: hook + apply + compress + clear (fused) -----
__global__ void k_round(u64* __restrict__ cand_g, const u32* __restrict__ ep,
                        u32* __restrict__ comp_g, u32* mstcnt,
                        u64* __restrict__ mkey, u32* __restrict__ mpay,
                        u32* __restrict__ done) {
    __shared__ u64 scand[CAP];  // 32 KB
    __shared__ u32 scomp[CAP];  // 16 KB
    __shared__ u32 shk[CAP];    // 16 KB
    __shared__ u32 nmerge;
    int k = blockIdx.x;
    if (done[k]) return;
    if (threadIdx.x == 0) nmerge = 0;
    for (int i = threadIdx.x; i < CAP; i += 1024) {
        scand[i] = cand_g[k * CAP + i];
        scomp[i] = comp_g[k * CAP + i];
    }
    __syncthreads();
    for (int i = threadIdx.x; i < CAP; i += 1024) {
        u64 cc = scand[i];
        if (cc == ~0ull) { shk[i] = (u32)i; continue; }
        u32 e = (u32)cc;
        u32 p32 = ep[(size_t)k * NE + e];
        u32 A = rootofs(scomp, p32 >> 16), B = rootofs(scomp, p32 & 0xFFFFu);
        shk[i] = (A == (u32)i) ? B : A;
    }
    __syncthreads();
    for (int i = threadIdx.x; i < CAP; i += 1024) {
        u32 o = shk[i];
        if (o == (u32)i) continue;
        bool mutual = (shk[o] == (u32)i);
        if (mutual && (u32)i < o) continue;
        scomp[i] = o;
        u64 cc = scand[i];
        u32 e = (u32)cc;
        u32 j = atomicAdd(&mstcnt[k], 1u);
        atomicAdd(&nmerge, 1u);
        if (j < CAP) { mkey[k * CAP + j] = cc; mpay[k * CAP + j] = ep[(size_t)k * NE + e]; }
    }
    __syncthreads();
    for (int i = threadIdx.x; i < CAP; i += 1024) scomp[i] = rootofs(scomp, i);
    __syncthreads();
    for (int i = threadIdx.x; i < CAP; i += 1024) {
        comp_g[k * CAP + i] = scomp[i];
        cand_g[k * CAP + i] = ~0ull;
    }
    if (threadIdx.x == 0 && nmerge == 0) done[k] = 1;  // zero merges => terminal
}

// ---------------- sort MSF edges per filtration (bitonic in LDS) ---------------
__global__ void k_sort(const u32* mstcnt, u64* __restrict__ mkey, u32* __restrict__ mpay) {
    __shared__ u64 skey[CAP];   // 32 KB
    __shared__ u32 spay[CAP];   // 16 KB
    int k = blockIdx.x;
    u32 cnt = mstcnt[k]; if (cnt > CAP) cnt = CAP;
    int n2 = 64; while (n2 < (int)cnt) n2 <<= 1;  // sort only next-pow2 >= cnt
    for (int i = threadIdx.x; i < CAP; i += 256) {
        skey[i] = (i < (int)cnt) ? mkey[k * CAP + i] : ~0ull;
        spay[i] = (i < (int)cnt) ? mpay[k * CAP + i] : 0u;
    }
    __syncthreads();
    for (int sz = 2; sz <= n2; sz <<= 1) {
        for (int st = sz >> 1; st >= 1; st >>= 1) {
            for (int i = threadIdx.x; i < n2; i += 256) {
                int j = i ^ st;
                if (j > i) {
                    bool up = ((i & sz) == 0);
                    u64 a = skey[i], b = skey[j];
                    bool sw = up ? (a > b) : (a < b);
                    if (sw) {
                        skey[i] = b; skey[j] = a;
                        u32 tp = spay[i]; spay[i] = spay[j]; spay[j] = tp;
                    }
                }
            }
            __syncthreads();
        }
    }
    for (int i = threadIdx.x; i < CAP; i += 256) {
        mkey[k * CAP + i] = skey[i];
        mpay[k * CAP + i] = spay[i];
    }
}

// ---- elder-rule pairing: wave-parallel speculative Kruskal windows (64 edges) --
// par[i]: parent (dense id). val[i]: f bits while root; death sortbits once dead.
// One wave per filtration. Sequential semantics preserved exactly.
// Sparse Gauss-Seidel: only lanes whose pre-window roots are SHARED with another
// lane (detected via LDS atomicAdd counters; single-wave lockstep => race-free)
// can participate in merge chains. Proof sketch: a non-shared lane's roots are
// used by no other lane, so no earlier lane kills them (no remap needed) and its
// killed root can never become a later lane's current root (remap targets are
// roots of colliding lanes only). Broadcast via readlane over the ballot mask of
// colliding lanes (~2-6/window) replaces the previous 63-step ds_bpermute scan.
__global__ __launch_bounds__(64) void k_pairw(
    const u32* nmin, const u32* __restrict__ mlist, const u32* mstcnt,
    const u64* __restrict__ mkey, const u32* __restrict__ mpay,
    const float* __restrict__ f, float* __restrict__ dval) {
    __shared__ u32 par[CAP];  // 16 KB
    __shared__ u32 val[CAP];  // 16 KB
    __shared__ u32 tag[CAP];  // 16 KB collision counters (zeroed, re-zeroed per window)
    int k = blockIdx.x;
    int lane = threadIdx.x;
    u32 nm = nmin[k]; if (nm > CAP) nm = CAP;
    u32 cnt = mstcnt[k]; if (cnt > CAP) cnt = CAP;
    for (int i = lane; i < CAP; i += 64) {
        par[i] = (u32)i;
        tag[i] = 0u;
        val[i] = (i < (int)nm) ? __float_as_uint(f[k * NV + mlist[k * CAP + i]]) : 0u;
    }
    __syncthreads();
    u32 nw = (cnt + 63) >> 6;
    // software prefetch of window 0
    u64 nkey = 0; u32 npay = 0;
    if ((u32)lane < cnt) {
        nkey = mkey[(size_t)k * CAP + lane];
        npay = mpay[(size_t)k * CAP + lane];
    }
    for (u32 w = 0; w < nw; w++) {
        u64 key = nkey; u32 pay = npay;
        bool valid = (w * 64 + (u32)lane) < cnt;
        u32 jn = (w + 1) * 64 + (u32)lane;
        if (jn < cnt) {  // prefetch next window (hides L2/HBM latency)
            nkey = mkey[(size_t)k * CAP + jn];
            npay = mpay[(size_t)k * CAP + jn];
        }
        u32 wb = (u32)(key >> 32);
        u32 la = pay >> 16, lb = pay & 0xFFFFu;
        // phase A: fused dual path-halving chase (overlapped LDS round trips)
        u32 rA = la, rB = lb;
        if (valid) {
            while (true) {
                u32 pA = par[rA], pB = par[rB];
                bool dA = (pA == rA), dB = (pB == rB);
                if (dA && dB) break;
                if (!dA) { u32 g = par[pA]; par[rA] = g; rA = g; }
                if (!dB) { u32 g = par[pB]; par[rB] = g; rB = g; }
            }
        }
        u32 vA = valid ? val[rA] : 0u;
        u32 vB = valid ? val[rB] : 0u;
        // collision detection: count root usages (lockstep => add, read, clear
        // are each wave-wide instructions in program order; no barriers needed)
        if (valid) { atomicAdd(&tag[rA], 1u); atomicAdd(&tag[rB], 1u); }
        u32 uA = valid ? tag[rA] : 0u;
        u32 uB = valid ? tag[rB] : 0u;
        if (valid) { tag[rA] = 0u; tag[rB] = 0u; }
        bool inS = valid && (uA > 1u || uB > 1u);
        // tentative merge
        u32 cA = rA, cvA = vA, cB = rB, cvB = vB;
        u32 t_fy = 0xFFFFFFFFu, t_fo = 0u, t_fvo = 0u;
        if (valid) {
            if (__uint_as_float(cvA) <= __uint_as_float(cvB)) { t_fo = cA; t_fvo = cvA; t_fy = cB; }
            else                                              { t_fo = cB; t_fvo = cvB; t_fy = cA; }
        }
        u32 pkd = (t_fy << 16) | t_fo;  // ids < 4096: fit 16+16
        // sparse Gauss-Seidel over colliding lanes only (ascending lane order)
        u64 m = __ballot(inS);
        while (m) {
            u32 s = (u32)__builtin_ctzll(m);
            m &= m - 1;
            u32 opk = __builtin_amdgcn_readlane(pkd, s);
            u32 ov  = __builtin_amdgcn_readlane(t_fvo, s);
            u32 oy = opk >> 16, oo = opk & 0xFFFFu;
            bool app = inS && ((u32)lane > s);
            bool mA = app && (cA == oy);
            bool mB = app && (cB == oy);
            if (mA) { cA = oo; cvA = ov; }
            if (mB) { cB = oo; cvB = ov; }
            if (mA || mB) {
                if (__uint_as_float(cvA) <= __uint_as_float(cvB)) { t_fo = cA; t_fvo = cvA; t_fy = cB; }
                else                                              { t_fo = cB; t_fvo = cvB; t_fy = cA; }
                pkd = (t_fy << 16) | t_fo;
            }
        }
        // commit: distinct t_fy across lanes; chains remain chaseable
        if (valid) { par[t_fy] = t_fo; val[t_fy] = wb; }
        __syncthreads();
    }
    // extraction: dead minima get death value from val slot
    for (int i = lane; i < (int)nm; i += 64) {
        if (par[i] != (u32)i)
            dval[k * NV + mlist[k * CAP + i]] = isb(val[i]);
    }
}

// ---------------- coordinate features -> bf16 directly into fused A ------------
__global__ void k_coordb(const float* __restrict__ f, const float* __restrict__ dval,
                         const float* __restrict__ tri_t, const float* __restrict__ gmu,
                         const float* __restrict__ gsig, const float* __restrict__ lw,
                         const float* __restrict__ rc, const float* __restrict__ rr,
                         u16* __restrict__ A) {
    int t = blockIdx.x * 256 + threadIdx.x;  // 160000
    int k = t / NV, v = t % NV;
    float b = f[t], d = dval[t];
    float o[12];
    float s = gsig[0];
    float inv2s2 = 1.0f / (2.0f * s * s);
    float r = fabsf(rr[0]);
#pragma unroll
    for (int j = 0; j < 3; j++) {
        float tri = d - fabsf(tri_t[j] - b);
        o[j] = tri > 0.f ? tri : 0.f;
        float dx = b - gmu[2 * j], dy = d - gmu[2 * j + 1];
        o[3 + j] = expf(-(dx * dx + dy * dy) * inv2s2);
        o[6 + j] = b * lw[2 * j] + d * lw[2 * j + 1];
        float q = fabsf(b - rc[2 * j]) + fabsf(d - rc[2 * j + 1]);
        o[9 + j] = 1.0f / (1.0f + q) - 1.0f / (1.0f + fabsf(r - q));
    }
    u16* dst = A + (size_t)v * KP + FIN + k * 12;  // 4B-aligned (2048+24k bytes)
    u32* d32 = (u32*)dst;
#pragma unroll
    for (int j = 0; j < 6; j++)
        d32[j] = (u32)f2bf(o[2 * j]) | ((u32)f2bf(o[2 * j + 1]) << 16);
}

// ---------------- GEMM2: out = A(bf16) @ W(bf16)^T + bias, MFMA ----------------
__global__ __launch_bounds__(256, 2) void k_gemm2(
    const u16* __restrict__ A, const u16* __restrict__ W,
    const float* __restrict__ bias, float* __restrict__ out) {
    __shared__ u16 As[128 * LDA];  // 18 KB
    __shared__ u16 Bs[128 * LDA];  // 18 KB
    int n0 = blockIdx.x * 128, m0 = blockIdx.y * 128;
    int t = threadIdx.x;
    int wave = t >> 6, lane = t & 63;
    int wm = (wave >> 1) * 64, wn = (wave & 1) * 64;
    int lrow = lane & 15, lq = lane >> 4;
    f32x4 acc[4][4];
#pragma unroll
    for (int i = 0; i < 4; i++)
#pragma unroll
        for (int j = 0; j < 4; j++) acc[i][j] = (f32x4){0.f, 0.f, 0.f, 0.f};

    int rowc[4], colc[4];
    uint4 av[4], bv[4];
#pragma unroll
    for (int i = 0; i < 4; i++) {
        int c = i * 256 + t;            // 0..1023 chunks of 8 bf16
        rowc[i] = c >> 3;
        colc[i] = (c & 7) * 8;
        av[i] = *(const uint4*)(A + (size_t)(m0 + rowc[i]) * KP + colc[i]);
        bv[i] = *(const uint4*)(W + (size_t)(n0 + rowc[i]) * KP + colc[i]);
    }
#pragma unroll 1
    for (int step = 0; step < KP / 64; step++) {
        __syncthreads();
#pragma unroll
        for (int i = 0; i < 4; i++) {
            *(uint4*)(As + rowc[i] * LDA + colc[i]) = av[i];
            *(uint4*)(Bs + rowc[i] * LDA + colc[i]) = bv[i];
        }
        __syncthreads();
        int k0n = (step + 1 < KP / 64) ? (step + 1) * 64 : 0;  // prefetch (clamped)
#pragma unroll
        for (int i = 0; i < 4; i++) {
            av[i] = *(const uint4*)(A + (size_t)(m0 + rowc[i]) * KP + k0n + colc[i]);
            bv[i] = *(const uint4*)(W + (size_t)(n0 + rowc[i]) * KP + k0n + colc[i]);
        }
#pragma unroll
        for (int kh = 0; kh < 2; kh++) {
            int kk = kh * 32 + lq * 8;
            bf16x8 af[4], bfr[4];
#pragma unroll
            for (int mt = 0; mt < 4; mt++)
                af[mt] = *(const bf16x8*)(As + (wm + mt * 16 + lrow) * LDA + kk);
#pragma unroll
            for (int nt = 0; nt < 4; nt++)
                bfr[nt] = *(const bf16x8*)(Bs + (wn + nt * 16 + lrow) * LDA + kk);
#pragma unroll
            for (int mt = 0; mt < 4; mt++)
#pragma unroll
                for (int nt = 0; nt < 4; nt++)
                    acc[mt][nt] = __builtin_amdgcn_mfma_f32_16x16x32_bf16(
                        af[mt], bfr[nt], acc[mt][nt], 0, 0, 0);
        }
    }
    // epilogue: row = (lane>>4)*4 + reg, col = lane&15  [verified C/D layout]
#pragma unroll
    for (int nt = 0; nt < 4; nt++) {
        int o = n0 + wn + nt * 16 + lrow;
        float bz = bias[o];
#pragma unroll
        for (int mt = 0; mt < 4; mt++) {
#pragma unroll
            for (int i = 0; i < 4; i++) {
                int v = m0 + wm + mt * 16 + lq * 4 + i;
                if (v < NV) out[(size_t)v * FOUT + o] = acc[mt][nt][i] + bz;
            }
        }
    }
}

extern "C" void kernel_launch(void* const* d_in, const int* in_sizes, int n_in,
                              void* d_out, int out_size, void* d_ws, size_t ws_size,
                              hipStream_t stream) {
    const float* x     = (const float*)d_in[0];
    const int*   ei    = (const int*)d_in[1];
    const float* fw    = (const float*)d_in[2];
    const float* fbv   = (const float*)d_in[3];
    const float* tri_t = (const float*)d_in[4];
    const float* gmu   = (const float*)d_in[5];
    const float* gsig  = (const float*)d_in[6];
    const float* lw    = (const float*)d_in[7];
    const float* rc    = (const float*)d_in[8];
    const float* rr    = (const float*)d_in[9];
    const float* ow    = (const float*)d_in[10];
    const float* ob    = (const float*)d_in[11];
    float* out = (float*)d_out;

    char* p = (char*)d_ws;
    auto alloc = [&](size_t bytes) -> void* {
        void* q = (void*)p;
        p += (bytes + 255) & ~(size_t)255;
        return q;
    };
    float* f     = (float*)alloc((size_t)NK * NV * 4);
    u64*   cd    = (u64*)  alloc((size_t)NK * NV * 8);
    u32*   basin = (u32*)  alloc((size_t)NK * NV * 4);
    u32*   dense = (u32*)  alloc((size_t)NK * NV * 4);
    u32*   mlist = (u32*)  alloc((size_t)NK * CAP * 4);
    u32*   cnts  = (u32*)  alloc(64 * 4);
    u64*   wkey  = (u64*)  alloc((size_t)NK * NE * 8);
    u32*   ep    = (u32*)  alloc((size_t)NK * NE * 4);
    u32*   comp  = (u32*)  alloc((size_t)NK * CAP * 4);
    u64*   cand  = (u64*)  alloc((size_t)NK * CAP * 8);
    u64*   mkey  = (u64*)  alloc((size_t)NK * CAP * 8);
    u32*   mpay  = (u32*)  alloc((size_t)NK * CAP * 4);
    float* dval  = (float*)alloc((size_t)NK * NV * 4);
    u16*   Ab    = (u16*)  alloc((size_t)MP * KP * 2);   // 46.3 MB fused [x|coord|pad]
    u16*   Wb    = (u16*)  alloc((size_t)FOUT * KP * 2); // 1.2 MB
    u32* nmin = cnts; u32* mstcnt = cnts + 8; u32* done = cnts + 16;

    k_init<<<128, 256, 0, stream>>>(comp, cand, cnts);
    k_fx<<<MP / 4, 256, 0, stream>>>(x, fw, fbv, f, Ab);
    k_castw<<<(FOUT * 144 + 255) / 256, 256, 0, stream>>>(ow, Wb);
    k_initdesc<<<625, 256, 0, stream>>>(f, cd, dval);
    k_descedge<<<3125, 256, 0, stream>>>(ei, f, cd);
    k_basmin<<<625, 256, 0, stream>>>(cd, basin, nmin, mlist, dense);
    k_edgeprep<<<3125, 256, 0, stream>>>(ei, f, basin, dense, wkey, ep);
    for (int r = 0; r < ROUNDS; r++) {
        k_candA<<<dim3(NB, NK), 256, 0, stream>>>(ep, wkey, comp, cand, done);
        k_round<<<NK, 1024, 0, stream>>>(cand, ep, comp, mstcnt, mkey, mpay, done);
    }
    k_sort<<<8, 256, 0, stream>>>(mstcnt, mkey, mpay);
    k_pairw<<<8, 64, 0, stream>>>(nmin, mlist, mstcnt, mkey, mpay, f, dval);
    k_coordb<<<625, 256, 0, stream>>>(f, dval, tri_t, gmu, gsig, lw, rc, rr, Ab);
    k_gemm2<<<dim3(4, 157), 256, 0, stream>>>(Ab, Wb, ob, out);
}

// Round 3
// 990.415 us; speedup vs baseline: 1.2496x; 1.1194x over previous
//
#include <hip/hip_runtime.h>
#include <stdint.h>

#define NV 20000
#define NE 100000
#define NK 8
#define FIN 1024
#define FOUT 512
#define FTOT 1120
#define KP 1152           // K padded to 18*64
#define MP 20096          // M padded to 157*128
#define CAP 4096
#define ROUNDS 13
#define NB 32             // edge-chunk blocks per filtration in k_candA
#define CHUNK (NE / NB)
#define LDA 72            // LDS row stride (bf16 elems): 64 + 8 pad

typedef unsigned int u32;
typedef unsigned long long u64;
typedef unsigned short u16;
typedef __attribute__((ext_vector_type(8))) short bf16x8;
typedef __attribute__((ext_vector_type(4))) float f32x4;

// float -> order-preserving unsigned bits, and inverse
__device__ __forceinline__ u32 sb(float x) {
    u32 u = __float_as_uint(x);
    return u ^ ((u & 0x80000000u) ? 0xFFFFFFFFu : 0x80000000u);
}
__device__ __forceinline__ float isb(u32 s) {
    u32 u = (s & 0x80000000u) ? (s ^ 0x80000000u) : ~s;
    return __uint_as_float(u);
}
// float -> bf16 (RNE)
__device__ __forceinline__ u16 f2bf(float f) {
    u32 u = __float_as_uint(f);
    return (u16)((u + 0x7FFFu + ((u >> 16) & 1u)) >> 16);
}

// ---- fused GEMM1 + bf16 cast of x into A ------------------------------------
__global__ __launch_bounds__(256) void k_fx(
    const float* __restrict__ x, const float* __restrict__ fw,
    const float* __restrict__ fb, float* __restrict__ f, u16* __restrict__ A) {
    __shared__ float w[NK * FIN];   // 32 KB
    __shared__ float xs[4][FIN];    // 16 KB
    for (int i = threadIdx.x; i < NK * FIN; i += 256) w[i] = fw[i];
    __syncthreads();
    int wave = threadIdx.x >> 6, lane = threadIdx.x & 63;
    int v = blockIdx.x * 4 + wave;  // 5024 * 4 = 20096 = MP
    float4* xd = (float4*)xs[wave];
    if (v < NV) {
        const float4* xr4 = (const float4*)(x + (size_t)v * FIN);
        for (int i = lane; i < FIN / 4; i += 64) xd[i] = xr4[i];
    } else {
        for (int i = lane; i < FIN / 4; i += 64) xd[i] = make_float4(0.f, 0.f, 0.f, 0.f);
    }
    // same-wave produce->consume: no barrier needed (lgkmcnt ordering)
    float acc[NK];
#pragma unroll
    for (int k = 0; k < NK; k++) acc[k] = 0.f;
    for (int c = 0; c < FIN / 64; c++) {
        int i = c * 64 + lane;
        float xv = xs[wave][i];
#pragma unroll
        for (int k = 0; k < NK; k++) acc[k] = fmaf(xv, w[k * FIN + i], acc[k]);
    }
#pragma unroll
    for (int off = 32; off >= 1; off >>= 1)
#pragma unroll
        for (int k = 0; k < NK; k++) acc[k] += __shfl_xor(acc[k], off, 64);
    if (v < NV && lane < NK) f[lane * NV + v] = acc[lane] + fb[lane];
    // bf16 emit: 144 chunks of 8 cols (1152 total), zeros beyond FIN
    for (int cc = lane; cc < 144; cc += 64) {
        int c0 = cc * 8;
        u32 pk[4];
        if (c0 < FIN) {
#pragma unroll
            for (int j = 0; j < 4; j++)
                pk[j] = (u32)f2bf(xs[wave][c0 + 2 * j]) |
                        ((u32)f2bf(xs[wave][c0 + 2 * j + 1]) << 16);
        } else {
#pragma unroll
            for (int j = 0; j < 4; j++) pk[j] = 0u;
        }
        *(uint4*)(A + (size_t)v * KP + c0) = make_uint4(pk[0], pk[1], pk[2], pk[3]);
    }
}

// ---------------- init: comp identity, cand = ~0, counters = 0 ----------------
__global__ void k_init(u32* __restrict__ comp, u64* __restrict__ cand, u32* cnts) {
    int t = blockIdx.x * 256 + threadIdx.x;  // 32768
    comp[t] = (u32)(t % CAP);
    cand[t] = ~0ull;
    if (t < 32) cnts[t] = 0;
}

// ---------------- cast out_w into bf16 W [512][1152] --------------------------
__global__ void k_castw(const float* __restrict__ ow, u16* __restrict__ W) {
    int t = blockIdx.x * 256 + threadIdx.x;  // 512*144
    if (t >= FOUT * 144) return;
    int n = t / 144, c = (t % 144) * 8;
    u32 pk[4];
    if (c < FTOT) {
        const float* wr = ow + (size_t)n * FTOT + c;
#pragma unroll
        for (int j = 0; j < 4; j++)
            pk[j] = (u32)f2bf(wr[2 * j]) | ((u32)f2bf(wr[2 * j + 1]) << 16);
    } else {
#pragma unroll
        for (int j = 0; j < 4; j++) pk[j] = 0u;
    }
    *(uint4*)(W + (size_t)n * KP + c) = make_uint4(pk[0], pk[1], pk[2], pk[3]);
}

// ---------------- descent pointers (+ dval default: death = birth) ------------
__global__ void k_initdesc(const float* __restrict__ f, u64* __restrict__ cd,
                           float* __restrict__ dval) {
    int t = blockIdx.x * 256 + threadIdx.x;  // 160000
    u32 v = (u32)(t % NV);
    float fv = f[t];
    cd[t] = ((u64)sb(fv) << 32) | v;
    dval[t] = fv;
}

__global__ void k_descedge(const int* __restrict__ ei, const float* __restrict__ f,
                           u64* __restrict__ cd) {
    int t = blockIdx.x * 256 + threadIdx.x;  // 800000
    int k = t / NE, e = t % NE;
    int a = ei[e], b = ei[NE + e];
    if (a == b) return;
    float fa = f[k * NV + a], fb2 = f[k * NV + b];
    int d, l; float fl;
    if (fa >= fb2) { d = a; l = b; fl = fb2; } else { d = b; l = a; fl = fa; }
    u64 key = ((u64)sb(fl) << 32) | (u32)l;
    atomicMin(&cd[k * NV + d], key);
}

// ---------------- basin chase + minima detection (fused) ----------------------
__global__ void k_basmin(const u64* __restrict__ cd, u32* __restrict__ basin,
                         u32* nmin, u32* __restrict__ mlist, u32* __restrict__ dense) {
    int t = blockIdx.x * 256 + threadIdx.x;
    int k = t / NV; u32 v = (u32)(t % NV);
    const u64* c = cd + (size_t)k * NV;
    u32 m = (u32)c[v];
    if (m == v) {
        basin[t] = v;
        u32 i = atomicAdd(&nmin[k], 1u);
        if (i < CAP) { mlist[k * CAP + i] = v; dense[t] = i; }
    } else {
        while (true) { u32 n = (u32)c[m]; if (n == m) break; m = n; }
        basin[t] = m;
    }
}

__global__ void k_edgeprep(const int* __restrict__ ei, const float* __restrict__ f,
                           const u32* __restrict__ basin, const u32* __restrict__ dense,
                           u64* __restrict__ wkey, u32* __restrict__ ep) {
    int t = blockIdx.x * 256 + threadIdx.x;  // 800000
    int k = t / NE, e = t % NE;
    int a = ei[e], b = ei[NE + e];
    if (a == b) { ep[t] = 0xFFFFFFFFu; return; }
    float fa = f[k * NV + a], fb2 = f[k * NV + b];
    float w = (fa >= fb2) ? fa : fb2;
    wkey[t] = ((u64)sb(w) << 32) | (u32)e;
    u32 ba = basin[k * NV + a], bb = basin[k * NV + b];
    if (ba == bb) { ep[t] = 0xFFFFFFFFu; return; }
    u32 da = dense[k * NV + ba], db = dense[k * NV + bb];
    ep[t] = (da << 16) | db;
}

// ---------------- Boruvka phase A: per-block LDS cand, sparse flush ------------
__device__ __forceinline__ u32 rootofs(const u32* c, u32 i) {
    while (true) { u32 p = c[i]; if (p == i) return i; i = p; }
}

__global__ void k_candA(const u32* __restrict__ ep, const u64* __restrict__ wkey,
                        const u32* __restrict__ comp_g, u64* __restrict__ cand_g,
                        const u32* __restrict__ done) {
    __shared__ u32 scomp[CAP];  // 16 KB
    __shared__ u64 scand[CAP];  // 32 KB
    int k = blockIdx.y, b = blockIdx.x;
    if (done[k]) return;  // converged: provably no more cross-component edges
    for (int i = threadIdx.x; i < CAP; i += 256) {
        scomp[i] = comp_g[k * CAP + i];
        scand[i] = ~0ull;
    }
    __syncthreads();
    int e0 = b * CHUNK;
    const u32* epk = ep + (size_t)k * NE;
    const u64* wkk = wkey + (size_t)k * NE;
    for (int e = e0 + threadIdx.x; e < e0 + CHUNK; e += 256) {
        u32 p32 = epk[e];
        if (p32 == 0xFFFFFFFFu) continue;
        u32 A = rootofs(scomp, p32 >> 16), B = rootofs(scomp, p32 & 0xFFFFu);
        if (A == B) continue;
        u64 w = wkk[e];
        atomicMin(&scand[A], w);
        atomicMin(&scand[B], w);
    }
    __syncthreads();
    u64* cnd = cand_g + (size_t)k * CAP;
    for (int i = threadIdx.x; i < CAP; i += 256) {
        u64 v = scand[i];
        if (v != ~0ull) atomicMin(&cnd[i], v);
    }
}

// ---------------- Boruvka phase B: hook + apply + compress + clear (fused) -----
__global__ void k_round(u64* __restrict__ cand_g, const u32* __restrict__ ep,
                        u32* __restrict__ comp_g, u32* mstcnt,
                        u64* __restrict__ mkey, u32* __restrict__ mpay,
                        u32* __restrict__ done) {
    __shared__ u64 scand[CAP];  // 32 KB
    __shared__ u32 scomp[CAP];  // 16 KB
    __shared__ u32 shk[CAP];    // 16 KB
    __shared__ u32 nmerge;
    int k = blockIdx.x;
    if (done[k]) return;
    if (threadIdx.x == 0) nmerge = 0;
    for (int i = threadIdx.x; i < CAP; i += 1024) {
        scand[i] = cand_g[k * CAP + i];
        scomp[i] = comp_g[k * CAP + i];
    }
    __syncthreads();
    for (int i = threadIdx.x; i < CAP; i += 1024) {
        u64 cc = scand[i];
        if (cc == ~0ull) { shk[i] = (u32)i; continue; }
        u32 e = (u32)cc;
        u32 p32 = ep[(size_t)k * NE + e];
        u32 A = rootofs(scomp, p32 >> 16), B = rootofs(scomp, p32 & 0xFFFFu);
        shk[i] = (A == (u32)i) ? B : A;
    }
    __syncthreads();
    for (int i = threadIdx.x; i < CAP; i += 1024) {
        u32 o = shk[i];
        if (o == (u32)i) continue;
        bool mutual = (shk[o] == (u32)i);
        if (mutual && (u32)i < o) continue;
        scomp[i] = o;
        u64 cc = scand[i];
        u32 e = (u32)cc;
        u32 j = atomicAdd(&mstcnt[k], 1u);
        atomicAdd(&nmerge, 1u);
        if (j < CAP) { mkey[k * CAP + j] = cc; mpay[k * CAP + j] = ep[(size_t)k * NE + e]; }
    }
    __syncthreads();
    for (int i = threadIdx.x; i < CAP; i += 1024) scomp[i] = rootofs(scomp, i);
    __syncthreads();
    for (int i = threadIdx.x; i < CAP; i += 1024) {
        comp_g[k * CAP + i] = scomp[i];
        cand_g[k * CAP + i] = ~0ull;
    }
    if (threadIdx.x == 0 && nmerge == 0) done[k] = 1;  // zero merges => terminal
}

// ---------------- sort MSF edges per filtration (bitonic in LDS) ---------------
__global__ void k_sort(const u32* mstcnt, u64* __restrict__ mkey, u32* __restrict__ mpay) {
    __shared__ u64 skey[CAP];   // 32 KB
    __shared__ u32 spay[CAP];   // 16 KB
    int k = blockIdx.x;
    u32 cnt = mstcnt[k]; if (cnt > CAP) cnt = CAP;
    int n2 = 64; while (n2 < (int)cnt) n2 <<= 1;  // sort only next-pow2 >= cnt
    for (int i = threadIdx.x; i < CAP; i += 256) {
        skey[i] = (i < (int)cnt) ? mkey[k * CAP + i] : ~0ull;
        spay[i] = (i < (int)cnt) ? mpay[k * CAP + i] : 0u;
    }
    __syncthreads();
    for (int sz = 2; sz <= n2; sz <<= 1) {
        for (int st = sz >> 1; st >= 1; st >>= 1) {
            for (int i = threadIdx.x; i < n2; i += 256) {
                int j = i ^ st;
                if (j > i) {
                    bool up = ((i & sz) == 0);
                    u64 a = skey[i], b = skey[j];
                    bool sw = up ? (a > b) : (a < b);
                    if (sw) {
                        skey[i] = b; skey[j] = a;
                        u32 tp = spay[i]; spay[i] = spay[j]; spay[j] = tp;
                    }
                }
            }
            __syncthreads();
        }
    }
    for (int i = threadIdx.x; i < CAP; i += 256) {
        mkey[k * CAP + i] = skey[i];
        mpay[k * CAP + i] = spay[i];
    }
}

// ---- elder-rule pairing: wave-parallel speculative Kruskal windows (64 edges) --
// par[i]: parent (dense id). val[i]: f bits while root; death sortbits once dead.
// One wave per filtration. Sequential semantics preserved exactly.
// PRODUCER-side sparse Gauss-Seidel: lane s must broadcast its merge only if its
// killed root t_fy is (or becomes) held by a later lane. tag[r] counts holders
// of root r: each lane counts its two pre-window roots, and every mid-window
// adopter of a survivor increments it too (required: a lane that adopted r and
// later kills r wouldn't otherwise be flagged, orphaning co-adopters). In the
// dominant regime (giant component absorbing fresh minima) every killed root
// has exactly one holder -> zero broadcasts -> the per-window scan vanishes.
// Single-wave lockstep makes the LDS atomic sequences race-free in program
// order. MSF forest property guarantees cA != cB throughout (no cycles).
__global__ __launch_bounds__(64) void k_pairw(
    const u32* nmin, const u32* __restrict__ mlist, const u32* mstcnt,
    const u64* __restrict__ mkey, const u32* __restrict__ mpay,
    const float* __restrict__ f, float* __restrict__ dval) {
    __shared__ u32 par[CAP];  // 16 KB
    __shared__ u32 val[CAP];  // 16 KB
    __shared__ u32 tag[CAP];  // 16 KB holder counters (zeroed after each window)
    int k = blockIdx.x;
    int lane = threadIdx.x;
    u32 nm = nmin[k]; if (nm > CAP) nm = CAP;
    u32 cnt = mstcnt[k]; if (cnt > CAP) cnt = CAP;
    for (int i = lane; i < CAP; i += 64) {
        par[i] = (u32)i;
        tag[i] = 0u;
        val[i] = (i < (int)nm) ? __float_as_uint(f[k * NV + mlist[k * CAP + i]]) : 0u;
    }
    __syncthreads();
    u32 nw = (cnt + 63) >> 6;
    // software prefetch of window 0
    u64 nkey = 0; u32 npay = 0;
    if ((u32)lane < cnt) {
        nkey = mkey[(size_t)k * CAP + lane];
        npay = mpay[(size_t)k * CAP + lane];
    }
    for (u32 w = 0; w < nw; w++) {
        u64 key = nkey; u32 pay = npay;
        bool valid = (w * 64 + (u32)lane) < cnt;
        u32 jn = (w + 1) * 64 + (u32)lane;
        if (jn < cnt) {  // prefetch next window (hides L2/HBM latency)
            nkey = mkey[(size_t)k * CAP + jn];
            npay = mpay[(size_t)k * CAP + jn];
        }
        u32 wb = (u32)(key >> 32);
        u32 la = pay >> 16, lb = pay & 0xFFFFu;
        // phase A: fused dual path-halving chase (overlapped LDS round trips)
        u32 rA = la, rB = lb;
        if (valid) {
            while (true) {
                u32 pA = par[rA], pB = par[rB];
                bool dA = (pA == rA), dB = (pB == rB);
                if (dA && dB) break;
                if (!dA) { u32 g = par[pA]; par[rA] = g; rA = g; }
                if (!dB) { u32 g = par[pB]; par[rB] = g; rB = g; }
            }
        }
        u32 vA = valid ? val[rA] : 0u;
        u32 vB = valid ? val[rB] : 0u;
        // count holders of each root (lockstep: adds complete before the reads)
        if (valid) { atomicAdd(&tag[rA], 1u); atomicAdd(&tag[rB], 1u); }
        // tentative merge
        u32 cA = rA, cvA = vA, cB = rB, cvB = vB;
        u32 t_fy = 0xFFFFFFFFu, t_fo = 0u, t_fvo = 0u;
        if (valid) {
            if (__uint_as_float(cvA) <= __uint_as_float(cvB)) { t_fo = cA; t_fvo = cvA; t_fy = cB; }
            else                                              { t_fo = cB; t_fvo = cvB; t_fy = cA; }
        }
        u32 pkd = (t_fy << 16) | (t_fo & 0xFFFFu);  // ids < 4096: fit 16+16
        // producer flag: my killed root has another holder
        bool pend = valid && (atomicAdd(&tag[t_fy], 0u) > 1u);
        u64 m = __ballot(pend);
        while (m) {
            u32 s = (u32)__builtin_ctzll(m);
            m &= m - 1;
            u32 opk = __builtin_amdgcn_readlane(pkd, (int)s);
            u32 ov  = __builtin_amdgcn_readlane(t_fvo, (int)s);
            u32 oy = opk >> 16, oo = opk & 0xFFFFu;
            if ((u32)lane == s) pend = false;
            bool app = valid && ((u32)lane > s);
            bool mA = app && (cA == oy);
            bool mB = app && (cB == oy);
            if (mA) { cA = oo; cvA = ov; }
            if (mB) { cB = oo; cvB = ov; }
            bool rm = mA || mB;
            if (__any(rm)) {
                if (rm) {
                    atomicAdd(&tag[oo], 1u);  // I now hold the survivor
                    if (__uint_as_float(cvA) <= __uint_as_float(cvB)) { t_fo = cA; t_fvo = cvA; t_fy = cB; }
                    else                                              { t_fo = cB; t_fvo = cvB; t_fy = cA; }
                    pkd = (t_fy << 16) | (t_fo & 0xFFFFu);
                    pend = atomicAdd(&tag[t_fy], 0u) > 1u;
                }
                m = __ballot(pend);
                m &= (s < 63u) ? (~0ull << (s + 1)) : 0ull;  // only lanes > s remain
            }
        }
        // zero every counted address (adoptees are other lanes' initial roots)
        if (valid) { tag[rA] = 0u; tag[rB] = 0u; }
        // commit: distinct t_fy across lanes; chains remain chaseable
        if (valid) { par[t_fy] = t_fo; val[t_fy] = wb; }
        __syncthreads();
    }
    // extraction: dead minima get death value from val slot
    for (int i = lane; i < (int)nm; i += 64) {
        if (par[i] != (u32)i)
            dval[k * NV + mlist[k * CAP + i]] = isb(val[i]);
    }
}

// ---------------- coordinate features -> bf16 directly into fused A ------------
__global__ void k_coordb(const float* __restrict__ f, const float* __restrict__ dval,
                         const float* __restrict__ tri_t, const float* __restrict__ gmu,
                         const float* __restrict__ gsig, const float* __restrict__ lw,
                         const float* __restrict__ rc, const float* __restrict__ rr,
                         u16* __restrict__ A) {
    int t = blockIdx.x * 256 + threadIdx.x;  // 160000
    int k = t / NV, v = t % NV;
    float b = f[t], d = dval[t];
    float o[12];
    float s = gsig[0];
    float inv2s2 = 1.0f / (2.0f * s * s);
    float r = fabsf(rr[0]);
#pragma unroll
    for (int j = 0; j < 3; j++) {
        float tri = d - fabsf(tri_t[j] - b);
        o[j] = tri > 0.f ? tri : 0.f;
        float dx = b - gmu[2 * j], dy = d - gmu[2 * j + 1];
        o[3 + j] = expf(-(dx * dx + dy * dy) * inv2s2);
        o[6 + j] = b * lw[2 * j] + d * lw[2 * j + 1];
        float q = fabsf(b - rc[2 * j]) + fabsf(d - rc[2 * j + 1]);
        o[9 + j] = 1.0f / (1.0f + q) - 1.0f / (1.0f + fabsf(r - q));
    }
    u16* dst = A + (size_t)v * KP + FIN + k * 12;  // 4B-aligned (2048+24k bytes)
    u32* d32 = (u32*)dst;
#pragma unroll
    for (int j = 0; j < 6; j++)
        d32[j] = (u32)f2bf(o[2 * j]) | ((u32)f2bf(o[2 * j + 1]) << 16);
}

// ---------------- GEMM2: out = A(bf16) @ W(bf16)^T + bias, MFMA ----------------
__global__ __launch_bounds__(256, 2) void k_gemm2(
    const u16* __restrict__ A, const u16* __restrict__ W,
    const float* __restrict__ bias, float* __restrict__ out) {
    __shared__ u16 As[128 * LDA];  // 18 KB
    __shared__ u16 Bs[128 * LDA];  // 18 KB
    int n0 = blockIdx.x * 128, m0 = blockIdx.y * 128;
    int t = threadIdx.x;
    int wave = t >> 6, lane = t & 63;
    int wm = (wave >> 1) * 64, wn = (wave & 1) * 64;
    int lrow = lane & 15, lq = lane >> 4;
    f32x4 acc[4][4];
#pragma unroll
    for (int i = 0; i < 4; i++)
#pragma unroll
        for (int j = 0; j < 4; j++) acc[i][j] = (f32x4){0.f, 0.f, 0.f, 0.f};

    int rowc[4], colc[4];
    uint4 av[4], bv[4];
#pragma unroll
    for (int i = 0; i < 4; i++) {
        int c = i * 256 + t;            // 0..1023 chunks of 8 bf16
        rowc[i] = c >> 3;
        colc[i] = (c & 7) * 8;
        av[i] = *(const uint4*)(A + (size_t)(m0 + rowc[i]) * KP + colc[i]);
        bv[i] = *(const uint4*)(W + (size_t)(n0 + rowc[i]) * KP + colc[i]);
    }
#pragma unroll 1
    for (int step = 0; step < KP / 64; step++) {
        __syncthreads();
#pragma unroll
        for (int i = 0; i < 4; i++) {
            *(uint4*)(As + rowc[i] * LDA + colc[i]) = av[i];
            *(uint4*)(Bs + rowc[i] * LDA + colc[i]) = bv[i];
        }
        __syncthreads();
        int k0n = (step + 1 < KP / 64) ? (step + 1) * 64 : 0;  // prefetch (clamped)
#pragma unroll
        for (int i = 0; i < 4; i++) {
            av[i] = *(const uint4*)(A + (size_t)(m0 + rowc[i]) * KP + k0n + colc[i]);
            bv[i] = *(const uint4*)(W + (size_t)(n0 + rowc[i]) * KP + k0n + colc[i]);
        }
#pragma unroll
        for (int kh = 0; kh < 2; kh++) {
            int kk = kh * 32 + lq * 8;
            bf16x8 af[4], bfr[4];
#pragma unroll
            for (int mt = 0; mt < 4; mt++)
                af[mt] = *(const bf16x8*)(As + (wm + mt * 16 + lrow) * LDA + kk);
#pragma unroll
            for (int nt = 0; nt < 4; nt++)
                bfr[nt] = *(const bf16x8*)(Bs + (wn + nt * 16 + lrow) * LDA + kk);
#pragma unroll
            for (int mt = 0; mt < 4; mt++)
#pragma unroll
                for (int nt = 0; nt < 4; nt++)
                    acc[mt][nt] = __builtin_amdgcn_mfma_f32_16x16x32_bf16(
                        af[mt], bfr[nt], acc[mt][nt], 0, 0, 0);
        }
    }
    // epilogue: row = (lane>>4)*4 + reg, col = lane&15  [verified C/D layout]
#pragma unroll
    for (int nt = 0; nt < 4; nt++) {
        int o = n0 + wn + nt * 16 + lrow;
        float bz = bias[o];
#pragma unroll
        for (int mt = 0; mt < 4; mt++) {
#pragma unroll
            for (int i = 0; i < 4; i++) {
                int v = m0 + wm + mt * 16 + lq * 4 + i;
                if (v < NV) out[(size_t)v * FOUT + o] = acc[mt][nt][i] + bz;
            }
        }
    }
}

extern "C" void kernel_launch(void* const* d_in, const int* in_sizes, int n_in,
                              void* d_out, int out_size, void* d_ws, size_t ws_size,
                              hipStream_t stream) {
    const float* x     = (const float*)d_in[0];
    const int*   ei    = (const int*)d_in[1];
    const float* fw    = (const float*)d_in[2];
    const float* fbv   = (const float*)d_in[3];
    const float* tri_t = (const float*)d_in[4];
    const float* gmu   = (const float*)d_in[5];
    const float* gsig  = (const float*)d_in[6];
    const float* lw    = (const float*)d_in[7];
    const float* rc    = (const float*)d_in[8];
    const float* rr    = (const float*)d_in[9];
    const float* ow    = (const float*)d_in[10];
    const float* ob    = (const float*)d_in[11];
    float* out = (float*)d_out;

    char* p = (char*)d_ws;
    auto alloc = [&](size_t bytes) -> void* {
        void* q = (void*)p;
        p += (bytes + 255) & ~(size_t)255;
        return q;
    };
    float* f     = (float*)alloc((size_t)NK * NV * 4);
    u64*   cd    = (u64*)  alloc((size_t)NK * NV * 8);
    u32*   basin = (u32*)  alloc((size_t)NK * NV * 4);
    u32*   dense = (u32*)  alloc((size_t)NK * NV * 4);
    u32*   mlist = (u32*)  alloc((size_t)NK * CAP * 4);
    u32*   cnts  = (u32*)  alloc(64 * 4);
    u64*   wkey  = (u64*)  alloc((size_t)NK * NE * 8);
    u32*   ep    = (u32*)  alloc((size_t)NK * NE * 4);
    u32*   comp  = (u32*)  alloc((size_t)NK * CAP * 4);
    u64*   cand  = (u64*)  alloc((size_t)NK * CAP * 8);
    u64*   mkey  = (u64*)  alloc((size_t)NK * CAP * 8);
    u32*   mpay  = (u32*)  alloc((size_t)NK * CAP * 4);
    float* dval  = (float*)alloc((size_t)NK * NV * 4);
    u16*   Ab    = (u16*)  alloc((size_t)MP * KP * 2);   // 46.3 MB fused [x|coord|pad]
    u16*   Wb    = (u16*)  alloc((size_t)FOUT * KP * 2); // 1.2 MB
    u32* nmin = cnts; u32* mstcnt = cnts + 8; u32* done = cnts + 16;

    k_init<<<128, 256, 0, stream>>>(comp, cand, cnts);
    k_fx<<<MP / 4, 256, 0, stream>>>(x, fw, fbv, f, Ab);
    k_castw<<<(FOUT * 144 + 255) / 256, 256, 0, stream>>>(ow, Wb);
    k_initdesc<<<625, 256, 0, stream>>>(f, cd, dval);
    k_descedge<<<3125, 256, 0, stream>>>(ei, f, cd);
    k_basmin<<<625, 256, 0, stream>>>(cd, basin, nmin, mlist, dense);
    k_edgeprep<<<3125, 256, 0, stream>>>(ei, f, basin, dense, wkey, ep);
    for (int r = 0; r < ROUNDS; r++) {
        k_candA<<<dim3(NB, NK), 256, 0, stream>>>(ep, wkey, comp, cand, done);
        k_round<<<NK, 1024, 0, stream>>>(cand, ep, comp, mstcnt, mkey, mpay, done);
    }
    k_sort<<<8, 256, 0, stream>>>(mstcnt, mkey, mpay);
    k_pairw<<<8, 64, 0, stream>>>(nmin, mlist, mstcnt, mkey, mpay, f, dval);
    k_coordb<<<625, 256, 0, stream>>>(f, dval, tri_t, gmu, gsig, lw, rc, rr, Ab);
    k_gemm2<<<dim3(4, 157), 256, 0, stream>>>(Ab, Wb, ob, out);
}

// Round 4
// 847.133 us; speedup vs baseline: 1.4610x; 1.1691x over previous
//
#include <hip/hip_runtime.h>
#include <stdint.h>

#define NV 20000
#define NE 100000
#define NK 8
#define FIN 1024
#define FOUT 512
#define FTOT 1120
#define KP 1152           // K padded to 18*64
#define MP 20096          // M padded to 157*128
#define CAP 4096
#define ROUNDS 13
#define NB 32             // edge-chunk blocks per filtration in k_candA
#define CHUNK (NE / NB)
#define LDA 72            // LDS row stride (bf16 elems): 64 + 8 pad

typedef unsigned int u32;
typedef unsigned long long u64;
typedef unsigned short u16;
typedef __attribute__((ext_vector_type(8))) short bf16x8;
typedef __attribute__((ext_vector_type(4))) float f32x4;

// float -> order-preserving unsigned bits, and inverse
__device__ __forceinline__ u32 sb(float x) {
    u32 u = __float_as_uint(x);
    return u ^ ((u & 0x80000000u) ? 0xFFFFFFFFu : 0x80000000u);
}
__device__ __forceinline__ float isb(u32 s) {
    u32 u = (s & 0x80000000u) ? (s ^ 0x80000000u) : ~s;
    return __uint_as_float(u);
}
// float -> bf16 (RNE)
__device__ __forceinline__ u16 f2bf(float f) {
    u32 u = __float_as_uint(f);
    return (u16)((u + 0x7FFFu + ((u >> 16) & 1u)) >> 16);
}

// ---- fused GEMM1 + bf16 cast of x into A ------------------------------------
__global__ __launch_bounds__(256) void k_fx(
    const float* __restrict__ x, const float* __restrict__ fw,
    const float* __restrict__ fb, float* __restrict__ f, u16* __restrict__ A) {
    __shared__ float w[NK * FIN];   // 32 KB
    __shared__ float xs[4][FIN];    // 16 KB
    for (int i = threadIdx.x; i < NK * FIN; i += 256) w[i] = fw[i];
    __syncthreads();
    int wave = threadIdx.x >> 6, lane = threadIdx.x & 63;
    int v = blockIdx.x * 4 + wave;  // 5024 * 4 = 20096 = MP
    float4* xd = (float4*)xs[wave];
    if (v < NV) {
        const float4* xr4 = (const float4*)(x + (size_t)v * FIN);
        for (int i = lane; i < FIN / 4; i += 64) xd[i] = xr4[i];
    } else {
        for (int i = lane; i < FIN / 4; i += 64) xd[i] = make_float4(0.f, 0.f, 0.f, 0.f);
    }
    // same-wave produce->consume: no barrier needed (lgkmcnt ordering)
    float acc[NK];
#pragma unroll
    for (int k = 0; k < NK; k++) acc[k] = 0.f;
    for (int c = 0; c < FIN / 64; c++) {
        int i = c * 64 + lane;
        float xv = xs[wave][i];
#pragma unroll
        for (int k = 0; k < NK; k++) acc[k] = fmaf(xv, w[k * FIN + i], acc[k]);
    }
#pragma unroll
    for (int off = 32; off >= 1; off >>= 1)
#pragma unroll
        for (int k = 0; k < NK; k++) acc[k] += __shfl_xor(acc[k], off, 64);
    if (v < NV && lane < NK) f[lane * NV + v] = acc[lane] + fb[lane];
    // bf16 emit: 144 chunks of 8 cols (1152 total), zeros beyond FIN
    for (int cc = lane; cc < 144; cc += 64) {
        int c0 = cc * 8;
        u32 pk[4];
        if (c0 < FIN) {
#pragma unroll
            for (int j = 0; j < 4; j++)
                pk[j] = (u32)f2bf(xs[wave][c0 + 2 * j]) |
                        ((u32)f2bf(xs[wave][c0 + 2 * j + 1]) << 16);
        } else {
#pragma unroll
            for (int j = 0; j < 4; j++) pk[j] = 0u;
        }
        *(uint4*)(A + (size_t)v * KP + c0) = make_uint4(pk[0], pk[1], pk[2], pk[3]);
    }
}

// ---------------- init: comp identity, cand = ~0, counters = 0 ----------------
__global__ void k_init(u32* __restrict__ comp, u64* __restrict__ cand, u32* cnts) {
    int t = blockIdx.x * 256 + threadIdx.x;  // 32768
    comp[t] = (u32)(t % CAP);
    cand[t] = ~0ull;
    if (t < 32) cnts[t] = 0;
}

// ---------------- cast out_w into bf16 W [512][1152] --------------------------
__global__ void k_castw(const float* __restrict__ ow, u16* __restrict__ W) {
    int t = blockIdx.x * 256 + threadIdx.x;  // 512*144
    if (t >= FOUT * 144) return;
    int n = t / 144, c = (t % 144) * 8;
    u32 pk[4];
    if (c < FTOT) {
        const float* wr = ow + (size_t)n * FTOT + c;
#pragma unroll
        for (int j = 0; j < 4; j++)
            pk[j] = (u32)f2bf(wr[2 * j]) | ((u32)f2bf(wr[2 * j + 1]) << 16);
    } else {
#pragma unroll
        for (int j = 0; j < 4; j++) pk[j] = 0u;
    }
    *(uint4*)(W + (size_t)n * KP + c) = make_uint4(pk[0], pk[1], pk[2], pk[3]);
}

// ---------------- descent pointers (+ dval default: death = birth) ------------
__global__ void k_initdesc(const float* __restrict__ f, u64* __restrict__ cd,
                           float* __restrict__ dval) {
    int t = blockIdx.x * 256 + threadIdx.x;  // 160000
    u32 v = (u32)(t % NV);
    float fv = f[t];
    cd[t] = ((u64)sb(fv) << 32) | v;
    dval[t] = fv;
}

__global__ void k_descedge(const int* __restrict__ ei, const float* __restrict__ f,
                           u64* __restrict__ cd) {
    int t = blockIdx.x * 256 + threadIdx.x;  // 800000
    int k = t / NE, e = t % NE;
    int a = ei[e], b = ei[NE + e];
    if (a == b) return;
    float fa = f[k * NV + a], fb2 = f[k * NV + b];
    int d, l; float fl;
    if (fa >= fb2) { d = a; l = b; fl = fb2; } else { d = b; l = a; fl = fa; }
    u64 key = ((u64)sb(fl) << 32) | (u32)l;
    atomicMin(&cd[k * NV + d], key);
}

// ---------------- basin: LDS pointer-doubling + minima detection ---------------
// One block per filtration. The successor array (low 32b of cd) is 80 KB ->
// fits in gfx950's 160 KB LDS. Quadruple-jump Jacobi passes converge depth/4x
// per pass; concurrent-read races are benign (any read value is a valid
// ancestor; monotone convergence to roots). Replaces 160K serial global-latency
// chases (~200cyc/step) with ~6 throughput-bound LDS passes.
__global__ __launch_bounds__(1024) void k_basmin(
    const u64* __restrict__ cd, u32* __restrict__ basin,
    u32* nmin, u32* __restrict__ mlist, u32* __restrict__ dense) {
    __shared__ u32 nxt[NV];   // 80 KB
    __shared__ u32 changed;
    int k = blockIdx.x;
    const u64* c = cd + (size_t)k * NV;
    for (int i = threadIdx.x; i < NV; i += 1024) nxt[i] = (u32)c[i];
    if (threadIdx.x == 0) changed = 0u;
    __syncthreads();
    for (int pass = 0; pass < 16; pass++) {
        bool ch = false;
        for (int i = threadIdx.x; i < NV; i += 1024) {
            u32 a = nxt[i];
            u32 b = nxt[a];
            if (b != a) {
                u32 c2 = nxt[b];
                u32 d2 = nxt[c2];
                nxt[i] = d2;
                ch = true;
            }
        }
        if (ch) changed = 1u;   // benign LDS race (all writers store 1)
        __syncthreads();
        u32 done = (changed == 0u);
        __syncthreads();
        if (threadIdx.x == 0) changed = 0u;
        __syncthreads();
        if (done) break;
    }
    for (int i = threadIdx.x; i < NV; i += 1024) {
        u32 r = nxt[i];
        basin[k * NV + i] = r;
        if (r == (u32)i) {
            u32 id = atomicAdd(&nmin[k], 1u);
            if (id < CAP) { mlist[k * CAP + id] = (u32)i; dense[k * NV + i] = id; }
        }
    }
}

__global__ void k_edgeprep(const int* __restrict__ ei, const float* __restrict__ f,
                           const u32* __restrict__ basin, const u32* __restrict__ dense,
                           u64* __restrict__ wkey, u32* __restrict__ ep) {
    int t = blockIdx.x * 256 + threadIdx.x;  // 800000
    int k = t / NE, e = t % NE;
    int a = ei[e], b = ei[NE + e];
    if (a == b) { ep[t] = 0xFFFFFFFFu; return; }
    float fa = f[k * NV + a], fb2 = f[k * NV + b];
    float w = (fa >= fb2) ? fa : fb2;
    wkey[t] = ((u64)sb(w) << 32) | (u32)e;
    u32 ba = basin[k * NV + a], bb = basin[k * NV + b];
    if (ba == bb) { ep[t] = 0xFFFFFFFFu; return; }
    u32 da = dense[k * NV + ba], db = dense[k * NV + bb];
    ep[t] = (da << 16) | db;
}

// ---------------- Boruvka phase A: per-block LDS cand, sparse flush ------------
__device__ __forceinline__ u32 rootofs(const u32* c, u32 i) {
    while (true) { u32 p = c[i]; if (p == i) return i; i = p; }
}

__global__ void k_candA(const u32* __restrict__ ep, const u64* __restrict__ wkey,
                        const u32* __restrict__ comp_g, u64* __restrict__ cand_g,
                        const u32* __restrict__ done) {
    __shared__ u32 scomp[CAP];  // 16 KB
    __shared__ u64 scand[CAP];  // 32 KB
    int k = blockIdx.y, b = blockIdx.x;
    if (done[k]) return;  // converged: provably no more cross-component edges
    for (int i = threadIdx.x; i < CAP; i += 256) {
        scomp[i] = comp_g[k * CAP + i];
        scand[i] = ~0ull;
    }
    __syncthreads();
    int e0 = b * CHUNK;
    const u32* epk = ep + (size_t)k * NE;
    const u64* wkk = wkey + (size_t)k * NE;
    for (int e = e0 + threadIdx.x; e < e0 + CHUNK; e += 256) {
        u32 p32 = epk[e];
        if (p32 == 0xFFFFFFFFu) continue;
        u32 A = rootofs(scomp, p32 >> 16), B = rootofs(scomp, p32 & 0xFFFFu);
        if (A == B) continue;
        u64 w = wkk[e];
        atomicMin(&scand[A], w);
        atomicMin(&scand[B], w);
    }
    __syncthreads();
    u64* cnd = cand_g + (size_t)k * CAP;
    for (int i = threadIdx.x; i < CAP; i += 256) {
        u64 v = scand[i];
        if (v != ~0ull) atomicMin(&cnd[i], v);
    }
}

// ---------------- Boruvka phase B: hook + apply + compress + clear (fused) -----
__global__ void k_round(u64* __restrict__ cand_g, const u32* __restrict__ ep,
                        u32* __restrict__ comp_g, u32* mstcnt,
                        u64* __restrict__ mkey, u32* __restrict__ mpay,
                        u32* __restrict__ done) {
    __shared__ u64 scand[CAP];  // 32 KB
    __shared__ u32 scomp[CAP];  // 16 KB
    __shared__ u32 shk[CAP];    // 16 KB
    __shared__ u32 nmerge;
    int k = blockIdx.x;
    if (done[k]) return;
    if (threadIdx.x == 0) nmerge = 0;
    for (int i = threadIdx.x; i < CAP; i += 1024) {
        scand[i] = cand_g[k * CAP + i];
        scomp[i] = comp_g[k * CAP + i];
    }
    __syncthreads();
    for (int i = threadIdx.x; i < CAP; i += 1024) {
        u64 cc = scand[i];
        if (cc == ~0ull) { shk[i] = (u32)i; continue; }
        u32 e = (u32)cc;
        u32 p32 = ep[(size_t)k * NE + e];
        u32 A = rootofs(scomp, p32 >> 16), B = rootofs(scomp, p32 & 0xFFFFu);
        shk[i] = (A == (u32)i) ? B : A;
    }
    __syncthreads();
    for (int i = threadIdx.x; i < CAP; i += 1024) {
        u32 o = shk[i];
        if (o == (u32)i) continue;
        bool mutual = (shk[o] == (u32)i);
        if (mutual && (u32)i < o) continue;
        scomp[i] = o;
        u64 cc = scand[i];
        u32 e = (u32)cc;
        u32 j = atomicAdd(&mstcnt[k], 1u);
        atomicAdd(&nmerge, 1u);
        if (j < CAP) { mkey[k * CAP + j] = cc; mpay[k * CAP + j] = ep[(size_t)k * NE + e]; }
    }
    __syncthreads();
    for (int i = threadIdx.x; i < CAP; i += 1024) scomp[i] = rootofs(scomp, i);
    __syncthreads();
    for (int i = threadIdx.x; i < CAP; i += 1024) {
        comp_g[k * CAP + i] = scomp[i];
        cand_g[k * CAP + i] = ~0ull;
    }
    if (threadIdx.x == 0 && nmerge == 0) done[k] = 1;  // zero merges => terminal
}

// ---------------- sort MSF edges per filtration (bitonic in LDS) ---------------
__global__ void k_sort(const u32* mstcnt, u64* __restrict__ mkey, u32* __restrict__ mpay) {
    __shared__ u64 skey[CAP];   // 32 KB
    __shared__ u32 spay[CAP];   // 16 KB
    int k = blockIdx.x;
    u32 cnt = mstcnt[k]; if (cnt > CAP) cnt = CAP;
    int n2 = 64; while (n2 < (int)cnt) n2 <<= 1;  // sort only next-pow2 >= cnt
    for (int i = threadIdx.x; i < CAP; i += 256) {
        skey[i] = (i < (int)cnt) ? mkey[k * CAP + i] : ~0ull;
        spay[i] = (i < (int)cnt) ? mpay[k * CAP + i] : 0u;
    }
    __syncthreads();
    for (int sz = 2; sz <= n2; sz <<= 1) {
        for (int st = sz >> 1; st >= 1; st >>= 1) {
            for (int i = threadIdx.x; i < n2; i += 256) {
                int j = i ^ st;
                if (j > i) {
                    bool up = ((i & sz) == 0);
                    u64 a = skey[i], b = skey[j];
                    bool sw = up ? (a > b) : (a < b);
                    if (sw) {
                        skey[i] = b; skey[j] = a;
                        u32 tp = spay[i]; spay[i] = spay[j]; spay[j] = tp;
                    }
                }
            }
            __syncthreads();
        }
    }
    for (int i = threadIdx.x; i < CAP; i += 256) {
        mkey[k * CAP + i] = skey[i];
        mpay[k * CAP + i] = spay[i];
    }
}

// ---- elder-rule pairing: wave-parallel speculative Kruskal windows (64 edges) --
// Producer-side sparse Gauss-Seidel (see R3 notes): lane s broadcasts only if
// its killed root is held by a later lane; holder counts in tag[], maintained
// through mid-window adoptions. Dominant regime: zero broadcasts per window.
__global__ __launch_bounds__(64) void k_pairw(
    const u32* nmin, const u32* __restrict__ mlist, const u32* mstcnt,
    const u64* __restrict__ mkey, const u32* __restrict__ mpay,
    const float* __restrict__ f, float* __restrict__ dval) {
    __shared__ u32 par[CAP];  // 16 KB
    __shared__ u32 val[CAP];  // 16 KB
    __shared__ u32 tag[CAP];  // 16 KB holder counters (zeroed after each window)
    int k = blockIdx.x;
    int lane = threadIdx.x;
    u32 nm = nmin[k]; if (nm > CAP) nm = CAP;
    u32 cnt = mstcnt[k]; if (cnt > CAP) cnt = CAP;
    for (int i = lane; i < CAP; i += 64) {
        par[i] = (u32)i;
        tag[i] = 0u;
        val[i] = (i < (int)nm) ? __float_as_uint(f[k * NV + mlist[k * CAP + i]]) : 0u;
    }
    __syncthreads();
    u32 nw = (cnt + 63) >> 6;
    // software prefetch of window 0
    u64 nkey = 0; u32 npay = 0;
    if ((u32)lane < cnt) {
        nkey = mkey[(size_t)k * CAP + lane];
        npay = mpay[(size_t)k * CAP + lane];
    }
    for (u32 w = 0; w < nw; w++) {
        u64 key = nkey; u32 pay = npay;
        bool valid = (w * 64 + (u32)lane) < cnt;
        u32 jn = (w + 1) * 64 + (u32)lane;
        if (jn < cnt) {  // prefetch next window (hides L2/HBM latency)
            nkey = mkey[(size_t)k * CAP + jn];
            npay = mpay[(size_t)k * CAP + jn];
        }
        u32 wb = (u32)(key >> 32);
        u32 la = pay >> 16, lb = pay & 0xFFFFu;
        // phase A: fused dual path-halving chase (overlapped LDS round trips)
        u32 rA = la, rB = lb;
        if (valid) {
            while (true) {
                u32 pA = par[rA], pB = par[rB];
                bool dA = (pA == rA), dB = (pB == rB);
                if (dA && dB) break;
                if (!dA) { u32 g = par[pA]; par[rA] = g; rA = g; }
                if (!dB) { u32 g = par[pB]; par[rB] = g; rB = g; }
            }
        }
        u32 vA = valid ? val[rA] : 0u;
        u32 vB = valid ? val[rB] : 0u;
        // count holders of each root (lockstep: adds complete before the reads)
        if (valid) { atomicAdd(&tag[rA], 1u); atomicAdd(&tag[rB], 1u); }
        // tentative merge
        u32 cA = rA, cvA = vA, cB = rB, cvB = vB;
        u32 t_fy = 0xFFFFFFFFu, t_fo = 0u, t_fvo = 0u;
        if (valid) {
            if (__uint_as_float(cvA) <= __uint_as_float(cvB)) { t_fo = cA; t_fvo = cvA; t_fy = cB; }
            else                                              { t_fo = cB; t_fvo = cvB; t_fy = cA; }
        }
        u32 pkd = (t_fy << 16) | (t_fo & 0xFFFFu);  // ids < 4096: fit 16+16
        // producer flag: my killed root has another holder
        bool pend = valid && (atomicAdd(&tag[t_fy], 0u) > 1u);
        u64 m = __ballot(pend);
        while (m) {
            u32 s = (u32)__builtin_ctzll(m);
            m &= m - 1;
            u32 opk = __builtin_amdgcn_readlane(pkd, (int)s);
            u32 ov  = __builtin_amdgcn_readlane(t_fvo, (int)s);
            u32 oy = opk >> 16, oo = opk & 0xFFFFu;
            if ((u32)lane == s) pend = false;
            bool app = valid && ((u32)lane > s);
            bool mA = app && (cA == oy);
            bool mB = app && (cB == oy);
            if (mA) { cA = oo; cvA = ov; }
            if (mB) { cB = oo; cvB = ov; }
            bool rm = mA || mB;
            if (__any(rm)) {
                if (rm) {
                    atomicAdd(&tag[oo], 1u);  // I now hold the survivor
                    if (__uint_as_float(cvA) <= __uint_as_float(cvB)) { t_fo = cA; t_fvo = cvA; t_fy = cB; }
                    else                                              { t_fo = cB; t_fvo = cvB; t_fy = cA; }
                    pkd = (t_fy << 16) | (t_fo & 0xFFFFu);
                    pend = atomicAdd(&tag[t_fy], 0u) > 1u;
                }
                m = __ballot(pend);
                m &= (s < 63u) ? (~0ull << (s + 1)) : 0ull;  // only lanes > s remain
            }
        }
        // zero every counted address (adoptees are other lanes' initial roots)
        if (valid) { tag[rA] = 0u; tag[rB] = 0u; }
        // commit: distinct t_fy across lanes; chains remain chaseable
        if (valid) { par[t_fy] = t_fo; val[t_fy] = wb; }
        __syncthreads();
    }
    // extraction: dead minima get death value from val slot
    for (int i = lane; i < (int)nm; i += 64) {
        if (par[i] != (u32)i)
            dval[k * NV + mlist[k * CAP + i]] = isb(val[i]);
    }
}

// ---------------- coordinate features -> bf16 directly into fused A ------------
__global__ void k_coordb(const float* __restrict__ f, const float* __restrict__ dval,
                         const float* __restrict__ tri_t, const float* __restrict__ gmu,
                         const float* __restrict__ gsig, const float* __restrict__ lw,
                         const float* __restrict__ rc, const float* __restrict__ rr,
                         u16* __restrict__ A) {
    int t = blockIdx.x * 256 + threadIdx.x;  // 160000
    int k = t / NV, v = t % NV;
    float b = f[t], d = dval[t];
    float o[12];
    float s = gsig[0];
    float inv2s2 = 1.0f / (2.0f * s * s);
    float r = fabsf(rr[0]);
#pragma unroll
    for (int j = 0; j < 3; j++) {
        float tri = d - fabsf(tri_t[j] - b);
        o[j] = tri > 0.f ? tri : 0.f;
        float dx = b - gmu[2 * j], dy = d - gmu[2 * j + 1];
        o[3 + j] = expf(-(dx * dx + dy * dy) * inv2s2);
        o[6 + j] = b * lw[2 * j] + d * lw[2 * j + 1];
        float q = fabsf(b - rc[2 * j]) + fabsf(d - rc[2 * j + 1]);
        o[9 + j] = 1.0f / (1.0f + q) - 1.0f / (1.0f + fabsf(r - q));
    }
    u16* dst = A + (size_t)v * KP + FIN + k * 12;  // 4B-aligned (2048+24k bytes)
    u32* d32 = (u32*)dst;
#pragma unroll
    for (int j = 0; j < 6; j++)
        d32[j] = (u32)f2bf(o[2 * j]) | ((u32)f2bf(o[2 * j + 1]) << 16);
}

// ---------------- GEMM2: out = A(bf16) @ W(bf16)^T + bias, MFMA ----------------
__global__ __launch_bounds__(256, 2) void k_gemm2(
    const u16* __restrict__ A, const u16* __restrict__ W,
    const float* __restrict__ bias, float* __restrict__ out) {
    __shared__ u16 As[128 * LDA];  // 18 KB
    __shared__ u16 Bs[128 * LDA];  // 18 KB
    int n0 = blockIdx.x * 128, m0 = blockIdx.y * 128;
    int t = threadIdx.x;
    int wave = t >> 6, lane = t & 63;
    int wm = (wave >> 1) * 64, wn = (wave & 1) * 64;
    int lrow = lane & 15, lq = lane >> 4;
    f32x4 acc[4][4];
#pragma unroll
    for (int i = 0; i < 4; i++)
#pragma unroll
        for (int j = 0; j < 4; j++) acc[i][j] = (f32x4){0.f, 0.f, 0.f, 0.f};

    int rowc[4], colc[4];
    uint4 av[4], bv[4];
#pragma unroll
    for (int i = 0; i < 4; i++) {
        int c = i * 256 + t;            // 0..1023 chunks of 8 bf16
        rowc[i] = c >> 3;
        colc[i] = (c & 7) * 8;
        av[i] = *(const uint4*)(A + (size_t)(m0 + rowc[i]) * KP + colc[i]);
        bv[i] = *(const uint4*)(W + (size_t)(n0 + rowc[i]) * KP + colc[i]);
    }
#pragma unroll 1
    for (int step = 0; step < KP / 64; step++) {
        __syncthreads();
#pragma unroll
        for (int i = 0; i < 4; i++) {
            *(uint4*)(As + rowc[i] * LDA + colc[i]) = av[i];
            *(uint4*)(Bs + rowc[i] * LDA + colc[i]) = bv[i];
        }
        __syncthreads();
        int k0n = (step + 1 < KP / 64) ? (step + 1) * 64 : 0;  // prefetch (clamped)
#pragma unroll
        for (int i = 0; i < 4; i++) {
            av[i] = *(const uint4*)(A + (size_t)(m0 + rowc[i]) * KP + k0n + colc[i]);
            bv[i] = *(const uint4*)(W + (size_t)(n0 + rowc[i]) * KP + k0n + colc[i]);
        }
#pragma unroll
        for (int kh = 0; kh < 2; kh++) {
            int kk = kh * 32 + lq * 8;
            bf16x8 af[4], bfr[4];
#pragma unroll
            for (int mt = 0; mt < 4; mt++)
                af[mt] = *(const bf16x8*)(As + (wm + mt * 16 + lrow) * LDA + kk);
#pragma unroll
            for (int nt = 0; nt < 4; nt++)
                bfr[nt] = *(const bf16x8*)(Bs + (wn + nt * 16 + lrow) * LDA + kk);
#pragma unroll
            for (int mt = 0; mt < 4; mt++)
#pragma unroll
                for (int nt = 0; nt < 4; nt++)
                    acc[mt][nt] = __builtin_amdgcn_mfma_f32_16x16x32_bf16(
                        af[mt], bfr[nt], acc[mt][nt], 0, 0, 0);
        }
    }
    // epilogue: row = (lane>>4)*4 + reg, col = lane&15  [verified C/D layout]
#pragma unroll
    for (int nt = 0; nt < 4; nt++) {
        int o = n0 + wn + nt * 16 + lrow;
        float bz = bias[o];
#pragma unroll
        for (int mt = 0; mt < 4; mt++) {
#pragma unroll
            for (int i = 0; i < 4; i++) {
                int v = m0 + wm + mt * 16 + lq * 4 + i;
                if (v < NV) out[(size_t)v * FOUT + o] = acc[mt][nt][i] + bz;
            }
        }
    }
}

extern "C" void kernel_launch(void* const* d_in, const int* in_sizes, int n_in,
                              void* d_out, int out_size, void* d_ws, size_t ws_size,
                              hipStream_t stream) {
    const float* x     = (const float*)d_in[0];
    const int*   ei    = (const int*)d_in[1];
    const float* fw    = (const float*)d_in[2];
    const float* fbv   = (const float*)d_in[3];
    const float* tri_t = (const float*)d_in[4];
    const float* gmu   = (const float*)d_in[5];
    const float* gsig  = (const float*)d_in[6];
    const float* lw    = (const float*)d_in[7];
    const float* rc    = (const float*)d_in[8];
    const float* rr    = (const float*)d_in[9];
    const float* ow    = (const float*)d_in[10];
    const float* ob    = (const float*)d_in[11];
    float* out = (float*)d_out;

    char* p = (char*)d_ws;
    auto alloc = [&](size_t bytes) -> void* {
        void* q = (void*)p;
        p += (bytes + 255) & ~(size_t)255;
        return q;
    };
    float* f     = (float*)alloc((size_t)NK * NV * 4);
    u64*   cd    = (u64*)  alloc((size_t)NK * NV * 8);
    u32*   basin = (u32*)  alloc((size_t)NK * NV * 4);
    u32*   dense = (u32*)  alloc((size_t)NK * NV * 4);
    u32*   mlist = (u32*)  alloc((size_t)NK * CAP * 4);
    u32*   cnts  = (u32*)  alloc(64 * 4);
    u64*   wkey  = (u64*)  alloc((size_t)NK * NE * 8);
    u32*   ep    = (u32*)  alloc((size_t)NK * NE * 4);
    u32*   comp  = (u32*)  alloc((size_t)NK * CAP * 4);
    u64*   cand  = (u64*)  alloc((size_t)NK * CAP * 8);
    u64*   mkey  = (u64*)  alloc((size_t)NK * CAP * 8);
    u32*   mpay  = (u32*)  alloc((size_t)NK * CAP * 4);
    float* dval  = (float*)alloc((size_t)NK * NV * 4);
    u16*   Ab    = (u16*)  alloc((size_t)MP * KP * 2);   // 46.3 MB fused [x|coord|pad]
    u16*   Wb    = (u16*)  alloc((size_t)FOUT * KP * 2); // 1.2 MB
    u32* nmin = cnts; u32* mstcnt = cnts + 8; u32* done = cnts + 16;

    k_init<<<128, 256, 0, stream>>>(comp, cand, cnts);
    k_fx<<<MP / 4, 256, 0, stream>>>(x, fw, fbv, f, Ab);
    k_castw<<<(FOUT * 144 + 255) / 256, 256, 0, stream>>>(ow, Wb);
    k_initdesc<<<625, 256, 0, stream>>>(f, cd, dval);
    k_descedge<<<3125, 256, 0, stream>>>(ei, f, cd);
    k_basmin<<<NK, 1024, 0, stream>>>(cd, basin, nmin, mlist, dense);
    k_edgeprep<<<3125, 256, 0, stream>>>(ei, f, basin, dense, wkey, ep);
    for (int r = 0; r < ROUNDS; r++) {
        k_candA<<<dim3(NB, NK), 256, 0, stream>>>(ep, wkey, comp, cand, done);
        k_round<<<NK, 1024, 0, stream>>>(cand, ep, comp, mstcnt, mkey, mpay, done);
    }
    k_sort<<<8, 256, 0, stream>>>(mstcnt, mkey, mpay);
    k_pairw<<<8, 64, 0, stream>>>(nmin, mlist, mstcnt, mkey, mpay, f, dval);
    k_coordb<<<625, 256, 0, stream>>>(f, dval, tri_t, gmu, gsig, lw, rc, rr, Ab);
    k_gemm2<<<dim3(4, 157), 256, 0, stream>>>(Ab, Wb, ob, out);
}

// Round 5
// 710.422 us; speedup vs baseline: 1.7421x; 1.1924x over previous
//
#include <hip/hip_runtime.h>
#include <stdint.h>

#define NV 20000
#define NE 100000
#define NK 8
#define FIN 1024
#define FOUT 512
#define FTOT 1120
#define KP 1152           // K padded to 18*64
#define MP 20096          // M padded to 157*128
#define CAP 4096
#define ROUNDS 13
#define NB 32             // edge-chunk blocks per filtration in k_candA
#define CHUNK (NE / NB)
#define LDA 72            // LDS row stride (bf16 elems): 64 + 8 pad

typedef unsigned int u32;
typedef unsigned long long u64;
typedef unsigned short u16;
typedef __attribute__((ext_vector_type(8))) short bf16x8;
typedef __attribute__((ext_vector_type(4))) float f32x4;

// float -> order-preserving unsigned bits, and inverse
__device__ __forceinline__ u32 sb(float x) {
    u32 u = __float_as_uint(x);
    return u ^ ((u & 0x80000000u) ? 0xFFFFFFFFu : 0x80000000u);
}
__device__ __forceinline__ float isb(u32 s) {
    u32 u = (s & 0x80000000u) ? (s ^ 0x80000000u) : ~s;
    return __uint_as_float(u);
}
// float -> bf16 (RNE)
__device__ __forceinline__ u16 f2bf(float f) {
    u32 u = __float_as_uint(f);
    return (u16)((u + 0x7FFFu + ((u >> 16) & 1u)) >> 16);
}

// ---- fused GEMM1 + bf16 cast of x into A ------------------------------------
__global__ __launch_bounds__(256) void k_fx(
    const float* __restrict__ x, const float* __restrict__ fw,
    const float* __restrict__ fb, float* __restrict__ f, u16* __restrict__ A) {
    __shared__ float w[NK * FIN];   // 32 KB
    __shared__ float xs[4][FIN];    // 16 KB
    for (int i = threadIdx.x; i < NK * FIN; i += 256) w[i] = fw[i];
    __syncthreads();
    int wave = threadIdx.x >> 6, lane = threadIdx.x & 63;
    int v = blockIdx.x * 4 + wave;  // 5024 * 4 = 20096 = MP
    float4* xd = (float4*)xs[wave];
    if (v < NV) {
        const float4* xr4 = (const float4*)(x + (size_t)v * FIN);
        for (int i = lane; i < FIN / 4; i += 64) xd[i] = xr4[i];
    } else {
        for (int i = lane; i < FIN / 4; i += 64) xd[i] = make_float4(0.f, 0.f, 0.f, 0.f);
    }
    // same-wave produce->consume: no barrier needed (lgkmcnt ordering)
    float acc[NK];
#pragma unroll
    for (int k = 0; k < NK; k++) acc[k] = 0.f;
    for (int c = 0; c < FIN / 64; c++) {
        int i = c * 64 + lane;
        float xv = xs[wave][i];
#pragma unroll
        for (int k = 0; k < NK; k++) acc[k] = fmaf(xv, w[k * FIN + i], acc[k]);
    }
#pragma unroll
    for (int off = 32; off >= 1; off >>= 1)
#pragma unroll
        for (int k = 0; k < NK; k++) acc[k] += __shfl_xor(acc[k], off, 64);
    if (v < NV && lane < NK) f[lane * NV + v] = acc[lane] + fb[lane];
    // bf16 emit: 144 chunks of 8 cols (1152 total), zeros beyond FIN
    for (int cc = lane; cc < 144; cc += 64) {
        int c0 = cc * 8;
        u32 pk[4];
        if (c0 < FIN) {
#pragma unroll
            for (int j = 0; j < 4; j++)
                pk[j] = (u32)f2bf(xs[wave][c0 + 2 * j]) |
                        ((u32)f2bf(xs[wave][c0 + 2 * j + 1]) << 16);
        } else {
#pragma unroll
            for (int j = 0; j < 4; j++) pk[j] = 0u;
        }
        *(uint4*)(A + (size_t)v * KP + c0) = make_uint4(pk[0], pk[1], pk[2], pk[3]);
    }
}

// ---------------- init: comp identity, cand = ~0, counters = 0 ----------------
__global__ void k_init(u32* __restrict__ comp, u64* __restrict__ cand, u32* cnts) {
    int t = blockIdx.x * 256 + threadIdx.x;  // 32768
    comp[t] = (u32)(t % CAP);
    cand[t] = ~0ull;
    if (t < 32) cnts[t] = 0;
}

// ---------------- cast out_w into bf16 W [512][1152] --------------------------
__global__ void k_castw(const float* __restrict__ ow, u16* __restrict__ W) {
    int t = blockIdx.x * 256 + threadIdx.x;  // 512*144
    if (t >= FOUT * 144) return;
    int n = t / 144, c = (t % 144) * 8;
    u32 pk[4];
    if (c < FTOT) {
        const float* wr = ow + (size_t)n * FTOT + c;
#pragma unroll
        for (int j = 0; j < 4; j++)
            pk[j] = (u32)f2bf(wr[2 * j]) | ((u32)f2bf(wr[2 * j + 1]) << 16);
    } else {
#pragma unroll
        for (int j = 0; j < 4; j++) pk[j] = 0u;
    }
    *(uint4*)(W + (size_t)n * KP + c) = make_uint4(pk[0], pk[1], pk[2], pk[3]);
}

// ---------------- descent pointers (+ dval default: death = birth) ------------
__global__ void k_initdesc(const float* __restrict__ f, u64* __restrict__ cd,
                           float* __restrict__ dval) {
    int t = blockIdx.x * 256 + threadIdx.x;  // 160000
    u32 v = (u32)(t % NV);
    float fv = f[t];
    cd[t] = ((u64)sb(fv) << 32) | v;
    dval[t] = fv;
}

__global__ void k_descedge(const int* __restrict__ ei, const float* __restrict__ f,
                           u64* __restrict__ cd) {
    int t = blockIdx.x * 256 + threadIdx.x;  // 800000
    int k = t / NE, e = t % NE;
    int a = ei[e], b = ei[NE + e];
    if (a == b) return;
    float fa = f[k * NV + a], fb2 = f[k * NV + b];
    int d, l; float fl;
    if (fa >= fb2) { d = a; l = b; fl = fb2; } else { d = b; l = a; fl = fa; }
    u64 key = ((u64)sb(fl) << 32) | (u32)l;
    atomicMin(&cd[k * NV + d], key);
}

// ---------------- basin: LDS pointer-doubling + minima detection ---------------
__global__ __launch_bounds__(1024) void k_basmin(
    const u64* __restrict__ cd, u32* __restrict__ basin,
    u32* nmin, u32* __restrict__ mlist, u32* __restrict__ dense) {
    __shared__ u32 nxt[NV];   // 80 KB
    __shared__ u32 changed;
    int k = blockIdx.x;
    const u64* c = cd + (size_t)k * NV;
    for (int i = threadIdx.x; i < NV; i += 1024) nxt[i] = (u32)c[i];
    if (threadIdx.x == 0) changed = 0u;
    __syncthreads();
    for (int pass = 0; pass < 16; pass++) {
        bool ch = false;
        for (int i = threadIdx.x; i < NV; i += 1024) {
            u32 a = nxt[i];
            u32 b = nxt[a];
            if (b != a) {
                u32 c2 = nxt[b];
                u32 d2 = nxt[c2];
                nxt[i] = d2;
                ch = true;
            }
        }
        if (ch) changed = 1u;   // benign LDS race (all writers store 1)
        __syncthreads();
        u32 done = (changed == 0u);
        __syncthreads();
        if (threadIdx.x == 0) changed = 0u;
        __syncthreads();
        if (done) break;
    }
    for (int i = threadIdx.x; i < NV; i += 1024) {
        u32 r = nxt[i];
        basin[k * NV + i] = r;
        if (r == (u32)i) {
            u32 id = atomicAdd(&nmin[k], 1u);
            if (id < CAP) { mlist[k * CAP + id] = (u32)i; dense[k * NV + i] = id; }
        }
    }
}

__global__ void k_edgeprep(const int* __restrict__ ei, const float* __restrict__ f,
                           const u32* __restrict__ basin, const u32* __restrict__ dense,
                           u64* __restrict__ wkey, u32* __restrict__ ep) {
    int t = blockIdx.x * 256 + threadIdx.x;  // 800000
    int k = t / NE, e = t % NE;
    int a = ei[e], b = ei[NE + e];
    if (a == b) { ep[t] = 0xFFFFFFFFu; return; }
    float fa = f[k * NV + a], fb2 = f[k * NV + b];
    float w = (fa >= fb2) ? fa : fb2;
    wkey[t] = ((u64)sb(w) << 32) | (u32)e;
    u32 ba = basin[k * NV + a], bb = basin[k * NV + b];
    if (ba == bb) { ep[t] = 0xFFFFFFFFu; return; }
    u32 da = dense[k * NV + ba], db = dense[k * NV + bb];
    ep[t] = (da << 16) | db;
}

// ---------------- Boruvka phase A: per-block LDS cand, sparse flush ------------
__device__ __forceinline__ u32 rootofs(const u32* c, u32 i) {
    while (true) { u32 p = c[i]; if (p == i) return i; i = p; }
}

__global__ void k_candA(const u32* __restrict__ ep, const u64* __restrict__ wkey,
                        const u32* __restrict__ comp_g, u64* __restrict__ cand_g,
                        const u32* __restrict__ done) {
    __shared__ u32 scomp[CAP];  // 16 KB
    __shared__ u64 scand[CAP];  // 32 KB
    int k = blockIdx.y, b = blockIdx.x;
    if (done[k]) return;  // converged: provably no more cross-component edges
    for (int i = threadIdx.x; i < CAP; i += 256) {
        scomp[i] = comp_g[k * CAP + i];
        scand[i] = ~0ull;
    }
    __syncthreads();
    int e0 = b * CHUNK;
    const u32* epk = ep + (size_t)k * NE;
    const u64* wkk = wkey + (size_t)k * NE;
    for (int e = e0 + threadIdx.x; e < e0 + CHUNK; e += 256) {
        u32 p32 = epk[e];
        if (p32 == 0xFFFFFFFFu) continue;
        u32 A = rootofs(scomp, p32 >> 16), B = rootofs(scomp, p32 & 0xFFFFu);
        if (A == B) continue;
        u64 w = wkk[e];
        atomicMin(&scand[A], w);
        atomicMin(&scand[B], w);
    }
    __syncthreads();
    u64* cnd = cand_g + (size_t)k * CAP;
    for (int i = threadIdx.x; i < CAP; i += 256) {
        u64 v = scand[i];
        if (v != ~0ull) atomicMin(&cnd[i], v);
    }
}

// ---------------- Boruvka phase B: hook + apply + compress + clear (fused) -----
__global__ void k_round(u64* __restrict__ cand_g, const u32* __restrict__ ep,
                        u32* __restrict__ comp_g, u32* mstcnt,
                        u64* __restrict__ mkey, u32* __restrict__ done) {
    __shared__ u64 scand[CAP];  // 32 KB
    __shared__ u32 scomp[CAP];  // 16 KB
    __shared__ u32 shk[CAP];    // 16 KB
    __shared__ u32 nmerge;
    int k = blockIdx.x;
    if (done[k]) return;
    if (threadIdx.x == 0) nmerge = 0;
    for (int i = threadIdx.x; i < CAP; i += 1024) {
        scand[i] = cand_g[k * CAP + i];
        scomp[i] = comp_g[k * CAP + i];
    }
    __syncthreads();
    for (int i = threadIdx.x; i < CAP; i += 1024) {
        u64 cc = scand[i];
        if (cc == ~0ull) { shk[i] = (u32)i; continue; }
        u32 e = (u32)cc;
        u32 p32 = ep[(size_t)k * NE + e];
        u32 A = rootofs(scomp, p32 >> 16), B = rootofs(scomp, p32 & 0xFFFFu);
        shk[i] = (A == (u32)i) ? B : A;
    }
    __syncthreads();
    for (int i = threadIdx.x; i < CAP; i += 1024) {
        u32 o = shk[i];
        if (o == (u32)i) continue;
        bool mutual = (shk[o] == (u32)i);
        if (mutual && (u32)i < o) continue;
        scomp[i] = o;
        u64 cc = scand[i];
        u32 j = atomicAdd(&mstcnt[k], 1u);
        atomicAdd(&nmerge, 1u);
        if (j < CAP) mkey[k * CAP + j] = cc;   // payload recomputed later from ep
    }
    __syncthreads();
    for (int i = threadIdx.x; i < CAP; i += 1024) scomp[i] = rootofs(scomp, i);
    __syncthreads();
    for (int i = threadIdx.x; i < CAP; i += 1024) {
        comp_g[k * CAP + i] = scomp[i];
        cand_g[k * CAP + i] = ~0ull;
    }
    if (threadIdx.x == 0 && nmerge == 0) done[k] = 1;  // zero merges => terminal
}

// ---------------- sort MSF edge keys per filtration (bitonic, keys-only) -------
// 1024 threads, pair-based indexing: n2/2 <= 2048 active compare-swaps per
// stage -> exactly 2 per thread, no idle (j>i) lanes. Payload is NOT carried:
// low 32 bits of the key are the edge id, so pay = ep[k*NE + (u32)key] is
// recomputed by the consumer. Tie-break semantics identical (weight, then e).
__global__ __launch_bounds__(1024) void k_sort(const u32* mstcnt, u64* __restrict__ mkey) {
    __shared__ u64 skey[CAP];   // 32 KB
    int k = blockIdx.x;
    u32 cnt = mstcnt[k]; if (cnt > CAP) cnt = CAP;
    int n2 = 64; while (n2 < (int)cnt) n2 <<= 1;  // sort next-pow2 >= cnt
    for (int i = threadIdx.x; i < n2; i += 1024)
        skey[i] = (i < (int)cnt) ? mkey[k * CAP + i] : ~0ull;
    __syncthreads();
    int half = n2 >> 1;
    for (int sz = 2; sz <= n2; sz <<= 1) {
        for (int st = sz >> 1; st >= 1; st >>= 1) {
            for (int t = threadIdx.x; t < half; t += 1024) {
                int i = ((t & ~(st - 1)) << 1) | (t & (st - 1));
                int j = i | st;
                bool up = ((i & sz) == 0);
                u64 a = skey[i], b = skey[j];
                if (up ? (a > b) : (a < b)) { skey[i] = b; skey[j] = a; }
            }
            __syncthreads();
        }
    }
    for (int i = threadIdx.x; i < (int)cnt; i += 1024)
        mkey[k * CAP + i] = skey[i];
}

// ---- elder-rule pairing: wave-parallel speculative Kruskal windows (64 edges) --
// Producer-side sparse Gauss-Seidel (see R3 notes). Payload (dense-id pair) is
// gathered from ep via the key's low 32 bits, one full window ahead.
__global__ __launch_bounds__(64) void k_pairw(
    const u32* nmin, const u32* __restrict__ mlist, const u32* mstcnt,
    const u64* __restrict__ mkey, const u32* __restrict__ ep,
    const float* __restrict__ f, float* __restrict__ dval) {
    __shared__ u32 par[CAP];  // 16 KB
    __shared__ u32 val[CAP];  // 16 KB
    __shared__ u32 tag[CAP];  // 16 KB holder counters (zeroed after each window)
    int k = blockIdx.x;
    int lane = threadIdx.x;
    u32 nm = nmin[k]; if (nm > CAP) nm = CAP;
    u32 cnt = mstcnt[k]; if (cnt > CAP) cnt = CAP;
    for (int i = lane; i < CAP; i += 64) {
        par[i] = (u32)i;
        tag[i] = 0u;
        val[i] = (i < (int)nm) ? __float_as_uint(f[k * NV + mlist[k * CAP + i]]) : 0u;
    }
    __syncthreads();
    u32 nw = (cnt + 63) >> 6;
    // software prefetch of window 0 (pay gather depends on key; window-ahead)
    u64 nkey = 0; u32 npay = 0;
    if ((u32)lane < cnt) {
        nkey = mkey[(size_t)k * CAP + lane];
        npay = ep[(size_t)k * NE + (u32)nkey];
    }
    for (u32 w = 0; w < nw; w++) {
        u64 key = nkey; u32 pay = npay;
        bool valid = (w * 64 + (u32)lane) < cnt;
        u32 jn = (w + 1) * 64 + (u32)lane;
        if (jn < cnt) {  // prefetch next window (hides L2/HBM latency)
            nkey = mkey[(size_t)k * CAP + jn];
            npay = ep[(size_t)k * NE + (u32)nkey];
        }
        u32 wb = (u32)(key >> 32);
        u32 la = pay >> 16, lb = pay & 0xFFFFu;
        // phase A: fused dual path-halving chase (overlapped LDS round trips)
        u32 rA = la, rB = lb;
        if (valid) {
            while (true) {
                u32 pA = par[rA], pB = par[rB];
                bool dA = (pA == rA), dB = (pB == rB);
                if (dA && dB) break;
                if (!dA) { u32 g = par[pA]; par[rA] = g; rA = g; }
                if (!dB) { u32 g = par[pB]; par[rB] = g; rB = g; }
            }
        }
        u32 vA = valid ? val[rA] : 0u;
        u32 vB = valid ? val[rB] : 0u;
        // count holders of each root (lockstep: adds complete before the reads)
        if (valid) { atomicAdd(&tag[rA], 1u); atomicAdd(&tag[rB], 1u); }
        // tentative merge
        u32 cA = rA, cvA = vA, cB = rB, cvB = vB;
        u32 t_fy = 0xFFFFFFFFu, t_fo = 0u, t_fvo = 0u;
        if (valid) {
            if (__uint_as_float(cvA) <= __uint_as_float(cvB)) { t_fo = cA; t_fvo = cvA; t_fy = cB; }
            else                                              { t_fo = cB; t_fvo = cvB; t_fy = cA; }
        }
        u32 pkd = (t_fy << 16) | (t_fo & 0xFFFFu);  // ids < 4096: fit 16+16
        // producer flag: my killed root has another holder
        bool pend = valid && (atomicAdd(&tag[t_fy], 0u) > 1u);
        u64 m = __ballot(pend);
        while (m) {
            u32 s = (u32)__builtin_ctzll(m);
            m &= m - 1;
            u32 opk = __builtin_amdgcn_readlane(pkd, (int)s);
            u32 ov  = __builtin_amdgcn_readlane(t_fvo, (int)s);
            u32 oy = opk >> 16, oo = opk & 0xFFFFu;
            if ((u32)lane == s) pend = false;
            bool app = valid && ((u32)lane > s);
            bool mA = app && (cA == oy);
            bool mB = app && (cB == oy);
            if (mA) { cA = oo; cvA = ov; }
            if (mB) { cB = oo; cvB = ov; }
            bool rm = mA || mB;
            if (__any(rm)) {
                if (rm) {
                    atomicAdd(&tag[oo], 1u);  // I now hold the survivor
                    if (__uint_as_float(cvA) <= __uint_as_float(cvB)) { t_fo = cA; t_fvo = cvA; t_fy = cB; }
                    else                                              { t_fo = cB; t_fvo = cvB; t_fy = cA; }
                    pkd = (t_fy << 16) | (t_fo & 0xFFFFu);
                    pend = atomicAdd(&tag[t_fy], 0u) > 1u;
                }
                m = __ballot(pend);
                m &= (s < 63u) ? (~0ull << (s + 1)) : 0ull;  // only lanes > s remain
            }
        }
        // zero every counted address (adoptees are other lanes' initial roots)
        if (valid) { tag[rA] = 0u; tag[rB] = 0u; }
        // commit: distinct t_fy across lanes; chains remain chaseable
        if (valid) { par[t_fy] = t_fo; val[t_fy] = wb; }
        __syncthreads();
    }
    // extraction: dead minima get death value from val slot
    for (int i = lane; i < (int)nm; i += 64) {
        if (par[i] != (u32)i)
            dval[k * NV + mlist[k * CAP + i]] = isb(val[i]);
    }
}

// ---------------- coordinate features -> bf16 directly into fused A ------------
__global__ void k_coordb(const float* __restrict__ f, const float* __restrict__ dval,
                         const float* __restrict__ tri_t, const float* __restrict__ gmu,
                         const float* __restrict__ gsig, const float* __restrict__ lw,
                         const float* __restrict__ rc, const float* __restrict__ rr,
                         u16* __restrict__ A) {
    int t = blockIdx.x * 256 + threadIdx.x;  // 160000
    int k = t / NV, v = t % NV;
    float b = f[t], d = dval[t];
    float o[12];
    float s = gsig[0];
    float inv2s2 = 1.0f / (2.0f * s * s);
    float r = fabsf(rr[0]);
#pragma unroll
    for (int j = 0; j < 3; j++) {
        float tri = d - fabsf(tri_t[j] - b);
        o[j] = tri > 0.f ? tri : 0.f;
        float dx = b - gmu[2 * j], dy = d - gmu[2 * j + 1];
        o[3 + j] = expf(-(dx * dx + dy * dy) * inv2s2);
        o[6 + j] = b * lw[2 * j] + d * lw[2 * j + 1];
        float q = fabsf(b - rc[2 * j]) + fabsf(d - rc[2 * j + 1]);
        o[9 + j] = 1.0f / (1.0f + q) - 1.0f / (1.0f + fabsf(r - q));
    }
    u16* dst = A + (size_t)v * KP + FIN + k * 12;  // 4B-aligned (2048+24k bytes)
    u32* d32 = (u32*)dst;
#pragma unroll
    for (int j = 0; j < 6; j++)
        d32[j] = (u32)f2bf(o[2 * j]) | ((u32)f2bf(o[2 * j + 1]) << 16);
}

// ---------------- GEMM2: out = A(bf16) @ W(bf16)^T + bias, MFMA ----------------
__global__ __launch_bounds__(256, 2) void k_gemm2(
    const u16* __restrict__ A, const u16* __restrict__ W,
    const float* __restrict__ bias, float* __restrict__ out) {
    __shared__ u16 As[128 * LDA];  // 18 KB
    __shared__ u16 Bs[128 * LDA];  // 18 KB
    int n0 = blockIdx.x * 128, m0 = blockIdx.y * 128;
    int t = threadIdx.x;
    int wave = t >> 6, lane = t & 63;
    int wm = (wave >> 1) * 64, wn = (wave & 1) * 64;
    int lrow = lane & 15, lq = lane >> 4;
    f32x4 acc[4][4];
#pragma unroll
    for (int i = 0; i < 4; i++)
#pragma unroll
        for (int j = 0; j < 4; j++) acc[i][j] = (f32x4){0.f, 0.f, 0.f, 0.f};

    int rowc[4], colc[4];
    uint4 av[4], bv[4];
#pragma unroll
    for (int i = 0; i < 4; i++) {
        int c = i * 256 + t;            // 0..1023 chunks of 8 bf16
        rowc[i] = c >> 3;
        colc[i] = (c & 7) * 8;
        av[i] = *(const uint4*)(A + (size_t)(m0 + rowc[i]) * KP + colc[i]);
        bv[i] = *(const uint4*)(W + (size_t)(n0 + rowc[i]) * KP + colc[i]);
    }
#pragma unroll 1
    for (int step = 0; step < KP / 64; step++) {
        __syncthreads();
#pragma unroll
        for (int i = 0; i < 4; i++) {
            *(uint4*)(As + rowc[i] * LDA + colc[i]) = av[i];
            *(uint4*)(Bs + rowc[i] * LDA + colc[i]) = bv[i];
        }
        __syncthreads();
        int k0n = (step + 1 < KP / 64) ? (step + 1) * 64 : 0;  // prefetch (clamped)
#pragma unroll
        for (int i = 0; i < 4; i++) {
            av[i] = *(const uint4*)(A + (size_t)(m0 + rowc[i]) * KP + k0n + colc[i]);
            bv[i] = *(const uint4*)(W + (size_t)(n0 + rowc[i]) * KP + k0n + colc[i]);
        }
#pragma unroll
        for (int kh = 0; kh < 2; kh++) {
            int kk = kh * 32 + lq * 8;
            bf16x8 af[4], bfr[4];
#pragma unroll
            for (int mt = 0; mt < 4; mt++)
                af[mt] = *(const bf16x8*)(As + (wm + mt * 16 + lrow) * LDA + kk);
#pragma unroll
            for (int nt = 0; nt < 4; nt++)
                bfr[nt] = *(const bf16x8*)(Bs + (wn + nt * 16 + lrow) * LDA + kk);
#pragma unroll
            for (int mt = 0; mt < 4; mt++)
#pragma unroll
                for (int nt = 0; nt < 4; nt++)
                    acc[mt][nt] = __builtin_amdgcn_mfma_f32_16x16x32_bf16(
                        af[mt], bfr[nt], acc[mt][nt], 0, 0, 0);
        }
    }
    // epilogue: row = (lane>>4)*4 + reg, col = lane&15  [verified C/D layout]
#pragma unroll
    for (int nt = 0; nt < 4; nt++) {
        int o = n0 + wn + nt * 16 + lrow;
        float bz = bias[o];
#pragma unroll
        for (int mt = 0; mt < 4; mt++) {
#pragma unroll
            for (int i = 0; i < 4; i++) {
                int v = m0 + wm + mt * 16 + lq * 4 + i;
                if (v < NV) out[(size_t)v * FOUT + o] = acc[mt][nt][i] + bz;
            }
        }
    }
}

extern "C" void kernel_launch(void* const* d_in, const int* in_sizes, int n_in,
                              void* d_out, int out_size, void* d_ws, size_t ws_size,
                              hipStream_t stream) {
    const float* x     = (const float*)d_in[0];
    const int*   ei    = (const int*)d_in[1];
    const float* fw    = (const float*)d_in[2];
    const float* fbv   = (const float*)d_in[3];
    const float* tri_t = (const float*)d_in[4];
    const float* gmu   = (const float*)d_in[5];
    const float* gsig  = (const float*)d_in[6];
    const float* lw    = (const float*)d_in[7];
    const float* rc    = (const float*)d_in[8];
    const float* rr    = (const float*)d_in[9];
    const float* ow    = (const float*)d_in[10];
    const float* ob    = (const float*)d_in[11];
    float* out = (float*)d_out;

    char* p = (char*)d_ws;
    auto alloc = [&](size_t bytes) -> void* {
        void* q = (void*)p;
        p += (bytes + 255) & ~(size_t)255;
        return q;
    };
    float* f     = (float*)alloc((size_t)NK * NV * 4);
    u64*   cd    = (u64*)  alloc((size_t)NK * NV * 8);
    u32*   basin = (u32*)  alloc((size_t)NK * NV * 4);
    u32*   dense = (u32*)  alloc((size_t)NK * NV * 4);
    u32*   mlist = (u32*)  alloc((size_t)NK * CAP * 4);
    u32*   cnts  = (u32*)  alloc(64 * 4);
    u64*   wkey  = (u64*)  alloc((size_t)NK * NE * 8);
    u32*   ep    = (u32*)  alloc((size_t)NK * NE * 4);
    u32*   comp  = (u32*)  alloc((size_t)NK * CAP * 4);
    u64*   cand  = (u64*)  alloc((size_t)NK * CAP * 8);
    u64*   mkey  = (u64*)  alloc((size_t)NK * CAP * 8);
    float* dval  = (float*)alloc((size_t)NK * NV * 4);
    u16*   Ab    = (u16*)  alloc((size_t)MP * KP * 2);   // 46.3 MB fused [x|coord|pad]
    u16*   Wb    = (u16*)  alloc((size_t)FOUT * KP * 2); // 1.2 MB
    u32* nmin = cnts; u32* mstcnt = cnts + 8; u32* done = cnts + 16;

    k_init<<<128, 256, 0, stream>>>(comp, cand, cnts);
    k_fx<<<MP / 4, 256, 0, stream>>>(x, fw, fbv, f, Ab);
    k_castw<<<(FOUT * 144 + 255) / 256, 256, 0, stream>>>(ow, Wb);
    k_initdesc<<<625, 256, 0, stream>>>(f, cd, dval);
    k_descedge<<<3125, 256, 0, stream>>>(ei, f, cd);
    k_basmin<<<NK, 1024, 0, stream>>>(cd, basin, nmin, mlist, dense);
    k_edgeprep<<<3125, 256, 0, stream>>>(ei, f, basin, dense, wkey, ep);
    for (int r = 0; r < ROUNDS; r++) {
        k_candA<<<dim3(NB, NK), 256, 0, stream>>>(ep, wkey, comp, cand, done);
        k_round<<<NK, 1024, 0, stream>>>(cand, ep, comp, mstcnt, mkey, done);
    }
    k_sort<<<8, 1024, 0, stream>>>(mstcnt, mkey);
    k_pairw<<<8, 64, 0, stream>>>(nmin, mlist, mstcnt, mkey, ep, f, dval);
    k_coordb<<<625, 256, 0, stream>>>(f, dval, tri_t, gmu, gsig, lw, rc, rr, Ab);
    k_gemm2<<<dim3(4, 157), 256, 0, stream>>>(Ab, Wb, ob, out);
}

// Round 6
// 667.301 us; speedup vs baseline: 1.8547x; 1.0646x over previous
//
#include <hip/hip_runtime.h>
#include <stdint.h>

#define NV 20000
#define NE 100000
#define NK 8
#define FIN 1024
#define FOUT 512
#define FTOT 1120
#define KP 1152           // K padded to 18*64
#define MP 20096          // M padded to 157*128
#define CAP 4096
#define ROUNDS 13
#define NB 32             // edge-chunk blocks per filtration in k_candA
#define CHUNK (NE / NB)
#define LDA 72            // LDS row stride (bf16 elems): 64 + 8 pad

typedef unsigned int u32;
typedef unsigned long long u64;
typedef unsigned short u16;
typedef __attribute__((ext_vector_type(8))) short bf16x8;
typedef __attribute__((ext_vector_type(4))) float f32x4;

// float -> order-preserving unsigned bits, and inverse
__device__ __forceinline__ u32 sb(float x) {
    u32 u = __float_as_uint(x);
    return u ^ ((u & 0x80000000u) ? 0xFFFFFFFFu : 0x80000000u);
}
__device__ __forceinline__ float isb(u32 s) {
    u32 u = (s & 0x80000000u) ? (s ^ 0x80000000u) : ~s;
    return __uint_as_float(u);
}
// float -> bf16 (RNE)
__device__ __forceinline__ u16 f2bf(float f) {
    u32 u = __float_as_uint(f);
    return (u16)((u + 0x7FFFu + ((u >> 16) & 1u)) >> 16);
}

// ---- fused GEMM1 + bf16 cast of x into A ------------------------------------
__global__ __launch_bounds__(256) void k_fx(
    const float* __restrict__ x, const float* __restrict__ fw,
    const float* __restrict__ fb, float* __restrict__ f, u16* __restrict__ A) {
    __shared__ float w[NK * FIN];   // 32 KB
    __shared__ float xs[4][FIN];    // 16 KB
    for (int i = threadIdx.x; i < NK * FIN; i += 256) w[i] = fw[i];
    __syncthreads();
    int wave = threadIdx.x >> 6, lane = threadIdx.x & 63;
    int v = blockIdx.x * 4 + wave;  // 5024 * 4 = 20096 = MP
    float4* xd = (float4*)xs[wave];
    if (v < NV) {
        const float4* xr4 = (const float4*)(x + (size_t)v * FIN);
        for (int i = lane; i < FIN / 4; i += 64) xd[i] = xr4[i];
    } else {
        for (int i = lane; i < FIN / 4; i += 64) xd[i] = make_float4(0.f, 0.f, 0.f, 0.f);
    }
    // same-wave produce->consume: no barrier needed (lgkmcnt ordering)
    float acc[NK];
#pragma unroll
    for (int k = 0; k < NK; k++) acc[k] = 0.f;
    for (int c = 0; c < FIN / 64; c++) {
        int i = c * 64 + lane;
        float xv = xs[wave][i];
#pragma unroll
        for (int k = 0; k < NK; k++) acc[k] = fmaf(xv, w[k * FIN + i], acc[k]);
    }
#pragma unroll
    for (int off = 32; off >= 1; off >>= 1)
#pragma unroll
        for (int k = 0; k < NK; k++) acc[k] += __shfl_xor(acc[k], off, 64);
    if (v < NV && lane < NK) f[lane * NV + v] = acc[lane] + fb[lane];
    // bf16 emit: 144 chunks of 8 cols (1152 total), zeros beyond FIN
    for (int cc = lane; cc < 144; cc += 64) {
        int c0 = cc * 8;
        u32 pk[4];
        if (c0 < FIN) {
#pragma unroll
            for (int j = 0; j < 4; j++)
                pk[j] = (u32)f2bf(xs[wave][c0 + 2 * j]) |
                        ((u32)f2bf(xs[wave][c0 + 2 * j + 1]) << 16);
        } else {
#pragma unroll
            for (int j = 0; j < 4; j++) pk[j] = 0u;
        }
        *(uint4*)(A + (size_t)v * KP + c0) = make_uint4(pk[0], pk[1], pk[2], pk[3]);
    }
}

// ---------------- init: comp identity, cand = ~0, counters = 0 ----------------
__global__ void k_init(u32* __restrict__ comp, u64* __restrict__ cand, u32* cnts) {
    int t = blockIdx.x * 256 + threadIdx.x;  // 32768
    comp[t] = (u32)(t % CAP);
    cand[t] = ~0ull;
    if (t < 32) cnts[t] = 0;
}

// ---------------- cast out_w into bf16 W [512][1152] --------------------------
__global__ void k_castw(const float* __restrict__ ow, u16* __restrict__ W) {
    int t = blockIdx.x * 256 + threadIdx.x;  // 512*144
    if (t >= FOUT * 144) return;
    int n = t / 144, c = (t % 144) * 8;
    u32 pk[4];
    if (c < FTOT) {
        const float* wr = ow + (size_t)n * FTOT + c;
#pragma unroll
        for (int j = 0; j < 4; j++)
            pk[j] = (u32)f2bf(wr[2 * j]) | ((u32)f2bf(wr[2 * j + 1]) << 16);
    } else {
#pragma unroll
        for (int j = 0; j < 4; j++) pk[j] = 0u;
    }
    *(uint4*)(W + (size_t)n * KP + c) = make_uint4(pk[0], pk[1], pk[2], pk[3]);
}

// ---------------- descent pointers (+ dval default: death = birth) ------------
__global__ void k_initdesc(const float* __restrict__ f, u64* __restrict__ cd,
                           float* __restrict__ dval) {
    int t = blockIdx.x * 256 + threadIdx.x;  // 160000
    u32 v = (u32)(t % NV);
    float fv = f[t];
    cd[t] = ((u64)sb(fv) << 32) | v;
    dval[t] = fv;
}

__global__ void k_descedge(const int* __restrict__ ei, const float* __restrict__ f,
                           u64* __restrict__ cd) {
    int t = blockIdx.x * 256 + threadIdx.x;  // 800000
    int k = t / NE, e = t % NE;
    int a = ei[e], b = ei[NE + e];
    if (a == b) return;
    float fa = f[k * NV + a], fb2 = f[k * NV + b];
    int d, l; float fl;
    if (fa >= fb2) { d = a; l = b; fl = fb2; } else { d = b; l = a; fl = fa; }
    u64 key = ((u64)sb(fl) << 32) | (u32)l;
    atomicMin(&cd[k * NV + d], key);
}

// ---------------- basin: LDS pointer-doubling + minima detection ---------------
__global__ __launch_bounds__(1024) void k_basmin(
    const u64* __restrict__ cd, u32* __restrict__ basin,
    u32* nmin, u32* __restrict__ mlist, u32* __restrict__ dense) {
    __shared__ u32 nxt[NV];   // 80 KB
    __shared__ u32 changed;
    int k = blockIdx.x;
    const u64* c = cd + (size_t)k * NV;
    for (int i = threadIdx.x; i < NV; i += 1024) nxt[i] = (u32)c[i];
    if (threadIdx.x == 0) changed = 0u;
    __syncthreads();
    for (int pass = 0; pass < 16; pass++) {
        bool ch = false;
        for (int i = threadIdx.x; i < NV; i += 1024) {
            u32 a = nxt[i];
            u32 b = nxt[a];
            if (b != a) {
                u32 c2 = nxt[b];
                u32 d2 = nxt[c2];
                nxt[i] = d2;
                ch = true;
            }
        }
        if (ch) changed = 1u;   // benign LDS race (all writers store 1)
        __syncthreads();
        u32 done = (changed == 0u);
        __syncthreads();
        if (threadIdx.x == 0) changed = 0u;
        __syncthreads();
        if (done) break;
    }
    for (int i = threadIdx.x; i < NV; i += 1024) {
        u32 r = nxt[i];
        basin[k * NV + i] = r;
        if (r == (u32)i) {
            u32 id = atomicAdd(&nmin[k], 1u);
            if (id < CAP) { mlist[k * CAP + id] = (u32)i; dense[k * NV + i] = id; }
        }
    }
}

__global__ void k_edgeprep(const int* __restrict__ ei, const float* __restrict__ f,
                           const u32* __restrict__ basin, const u32* __restrict__ dense,
                           u64* __restrict__ wkey, u32* __restrict__ ep) {
    int t = blockIdx.x * 256 + threadIdx.x;  // 800000
    int k = t / NE, e = t % NE;
    int a = ei[e], b = ei[NE + e];
    if (a == b) { ep[t] = 0xFFFFFFFFu; return; }
    float fa = f[k * NV + a], fb2 = f[k * NV + b];
    float w = (fa >= fb2) ? fa : fb2;
    wkey[t] = ((u64)sb(w) << 32) | (u32)e;
    u32 ba = basin[k * NV + a], bb = basin[k * NV + b];
    if (ba == bb) { ep[t] = 0xFFFFFFFFu; return; }
    u32 da = dense[k * NV + ba], db = dense[k * NV + bb];
    ep[t] = (da << 16) | db;
}

// ---------------- Boruvka phase A: per-block LDS cand, sparse flush ------------
__device__ __forceinline__ u32 rootofs(const u32* c, u32 i) {
    while (true) { u32 p = c[i]; if (p == i) return i; i = p; }
}

__global__ void k_candA(const u32* __restrict__ ep, const u64* __restrict__ wkey,
                        const u32* __restrict__ comp_g, u64* __restrict__ cand_g,
                        const u32* __restrict__ done) {
    __shared__ u32 scomp[CAP];  // 16 KB
    __shared__ u64 scand[CAP];  // 32 KB
    int k = blockIdx.y, b = blockIdx.x;
    if (done[k]) return;  // converged: provably no more cross-component edges
    for (int i = threadIdx.x; i < CAP; i += 256) {
        scomp[i] = comp_g[k * CAP + i];
        scand[i] = ~0ull;
    }
    __syncthreads();
    int e0 = b * CHUNK;
    const u32* epk = ep + (size_t)k * NE;
    const u64* wkk = wkey + (size_t)k * NE;
    for (int e = e0 + threadIdx.x; e < e0 + CHUNK; e += 256) {
        u32 p32 = epk[e];
        if (p32 == 0xFFFFFFFFu) continue;
        u32 A = rootofs(scomp, p32 >> 16), B = rootofs(scomp, p32 & 0xFFFFu);
        if (A == B) continue;
        u64 w = wkk[e];
        atomicMin(&scand[A], w);
        atomicMin(&scand[B], w);
    }
    __syncthreads();
    u64* cnd = cand_g + (size_t)k * CAP;
    for (int i = threadIdx.x; i < CAP; i += 256) {
        u64 v = scand[i];
        if (v != ~0ull) atomicMin(&cnd[i], v);
    }
}

// ---------------- Boruvka phase B: hook + apply + compress + clear (fused) -----
__global__ void k_round(u64* __restrict__ cand_g, const u32* __restrict__ ep,
                        u32* __restrict__ comp_g, u32* mstcnt,
                        u64* __restrict__ mkey, u32* __restrict__ done) {
    __shared__ u64 scand[CAP];  // 32 KB
    __shared__ u32 scomp[CAP];  // 16 KB
    __shared__ u32 shk[CAP];    // 16 KB
    __shared__ u32 nmerge;
    int k = blockIdx.x;
    if (done[k]) return;
    if (threadIdx.x == 0) nmerge = 0;
    for (int i = threadIdx.x; i < CAP; i += 1024) {
        scand[i] = cand_g[k * CAP + i];
        scomp[i] = comp_g[k * CAP + i];
    }
    __syncthreads();
    for (int i = threadIdx.x; i < CAP; i += 1024) {
        u64 cc = scand[i];
        if (cc == ~0ull) { shk[i] = (u32)i; continue; }
        u32 e = (u32)cc;
        u32 p32 = ep[(size_t)k * NE + e];
        u32 A = rootofs(scomp, p32 >> 16), B = rootofs(scomp, p32 & 0xFFFFu);
        shk[i] = (A == (u32)i) ? B : A;
    }
    __syncthreads();
    for (int i = threadIdx.x; i < CAP; i += 1024) {
        u32 o = shk[i];
        if (o == (u32)i) continue;
        bool mutual = (shk[o] == (u32)i);
        if (mutual && (u32)i < o) continue;
        scomp[i] = o;
        u64 cc = scand[i];
        u32 j = atomicAdd(&mstcnt[k], 1u);
        atomicAdd(&nmerge, 1u);
        if (j < CAP) mkey[k * CAP + j] = cc;   // payload recomputed later from ep
    }
    __syncthreads();
    for (int i = threadIdx.x; i < CAP; i += 1024) scomp[i] = rootofs(scomp, i);
    __syncthreads();
    for (int i = threadIdx.x; i < CAP; i += 1024) {
        comp_g[k * CAP + i] = scomp[i];
        cand_g[k * CAP + i] = ~0ull;
    }
    if (threadIdx.x == 0 && nmerge == 0) done[k] = 1;  // zero merges => terminal
}

// ---------------- sort MSF edge keys per filtration (bitonic, keys-only) -------
__global__ __launch_bounds__(1024) void k_sort(const u32* mstcnt, u64* __restrict__ mkey) {
    __shared__ u64 skey[CAP];   // 32 KB
    int k = blockIdx.x;
    u32 cnt = mstcnt[k]; if (cnt > CAP) cnt = CAP;
    int n2 = 64; while (n2 < (int)cnt) n2 <<= 1;  // sort next-pow2 >= cnt
    for (int i = threadIdx.x; i < n2; i += 1024)
        skey[i] = (i < (int)cnt) ? mkey[k * CAP + i] : ~0ull;
    __syncthreads();
    int half = n2 >> 1;
    for (int sz = 2; sz <= n2; sz <<= 1) {
        for (int st = sz >> 1; st >= 1; st >>= 1) {
            for (int t = threadIdx.x; t < half; t += 1024) {
                int i = ((t & ~(st - 1)) << 1) | (t & (st - 1));
                int j = i | st;
                bool up = ((i & sz) == 0);
                u64 a = skey[i], b = skey[j];
                if (up ? (a > b) : (a < b)) { skey[i] = b; skey[j] = a; }
            }
            __syncthreads();
        }
    }
    for (int i = threadIdx.x; i < (int)cnt; i += 1024)
        mkey[k * CAP + i] = skey[i];
}

// ---- elder-rule pairing: wave-parallel speculative Kruskal windows (64 edges) --
// Producer-side sparse Gauss-Seidel (see R3 notes). Payload (dense-id pair) is
// gathered from ep via the key's low 32 bits, one full window ahead.
__global__ __launch_bounds__(64) void k_pairw(
    const u32* nmin, const u32* __restrict__ mlist, const u32* mstcnt,
    const u64* __restrict__ mkey, const u32* __restrict__ ep,
    const float* __restrict__ f, float* __restrict__ dval) {
    __shared__ u32 par[CAP];  // 16 KB
    __shared__ u32 val[CAP];  // 16 KB
    __shared__ u32 tag[CAP];  // 16 KB holder counters (zeroed after each window)
    int k = blockIdx.x;
    int lane = threadIdx.x;
    u32 nm = nmin[k]; if (nm > CAP) nm = CAP;
    u32 cnt = mstcnt[k]; if (cnt > CAP) cnt = CAP;
    for (int i = lane; i < CAP; i += 64) {
        par[i] = (u32)i;
        tag[i] = 0u;
        val[i] = (i < (int)nm) ? __float_as_uint(f[k * NV + mlist[k * CAP + i]]) : 0u;
    }
    __syncthreads();
    u32 nw = (cnt + 63) >> 6;
    // software prefetch of window 0 (pay gather depends on key; window-ahead)
    u64 nkey = 0; u32 npay = 0;
    if ((u32)lane < cnt) {
        nkey = mkey[(size_t)k * CAP + lane];
        npay = ep[(size_t)k * NE + (u32)nkey];
    }
    for (u32 w = 0; w < nw; w++) {
        u64 key = nkey; u32 pay = npay;
        bool valid = (w * 64 + (u32)lane) < cnt;
        u32 jn = (w + 1) * 64 + (u32)lane;
        if (jn < cnt) {  // prefetch next window (hides L2/HBM latency)
            nkey = mkey[(size_t)k * CAP + jn];
            npay = ep[(size_t)k * NE + (u32)nkey];
        }
        u32 wb = (u32)(key >> 32);
        u32 la = pay >> 16, lb = pay & 0xFFFFu;
        // phase A: fused dual path-halving chase (overlapped LDS round trips)
        u32 rA = la, rB = lb;
        if (valid) {
            while (true) {
                u32 pA = par[rA], pB = par[rB];
                bool dA = (pA == rA), dB = (pB == rB);
                if (dA && dB) break;
                if (!dA) { u32 g = par[pA]; par[rA] = g; rA = g; }
                if (!dB) { u32 g = par[pB]; par[rB] = g; rB = g; }
            }
        }
        u32 vA = valid ? val[rA] : 0u;
        u32 vB = valid ? val[rB] : 0u;
        // count holders of each root (lockstep: adds complete before the reads)
        if (valid) { atomicAdd(&tag[rA], 1u); atomicAdd(&tag[rB], 1u); }
        // tentative merge
        u32 cA = rA, cvA = vA, cB = rB, cvB = vB;
        u32 t_fy = 0xFFFFFFFFu, t_fo = 0u, t_fvo = 0u;
        if (valid) {
            if (__uint_as_float(cvA) <= __uint_as_float(cvB)) { t_fo = cA; t_fvo = cvA; t_fy = cB; }
            else                                              { t_fo = cB; t_fvo = cvB; t_fy = cA; }
        }
        u32 pkd = (t_fy << 16) | (t_fo & 0xFFFFu);  // ids < 4096: fit 16+16
        // producer flag: my killed root has another holder
        bool pend = valid && (atomicAdd(&tag[t_fy], 0u) > 1u);
        u64 m = __ballot(pend);
        while (m) {
            u32 s = (u32)__builtin_ctzll(m);
            m &= m - 1;
            u32 opk = __builtin_amdgcn_readlane(pkd, (int)s);
            u32 ov  = __builtin_amdgcn_readlane(t_fvo, (int)s);
            u32 oy = opk >> 16, oo = opk & 0xFFFFu;
            if ((u32)lane == s) pend = false;
            bool app = valid && ((u32)lane > s);
            bool mA = app && (cA == oy);
            bool mB = app && (cB == oy);
            if (mA) { cA = oo; cvA = ov; }
            if (mB) { cB = oo; cvB = ov; }
            bool rm = mA || mB;
            if (__any(rm)) {
                if (rm) {
                    atomicAdd(&tag[oo], 1u);  // I now hold the survivor
                    if (__uint_as_float(cvA) <= __uint_as_float(cvB)) { t_fo = cA; t_fvo = cvA; t_fy = cB; }
                    else                                              { t_fo = cB; t_fvo = cvB; t_fy = cA; }
                    pkd = (t_fy << 16) | (t_fo & 0xFFFFu);
                    pend = atomicAdd(&tag[t_fy], 0u) > 1u;
                }
                m = __ballot(pend);
                m &= (s < 63u) ? (~0ull << (s + 1)) : 0ull;  // only lanes > s remain
            }
        }
        // zero every counted address (adoptees are other lanes' initial roots)
        if (valid) { tag[rA] = 0u; tag[rB] = 0u; }
        // commit: distinct t_fy across lanes; chains remain chaseable
        if (valid) { par[t_fy] = t_fo; val[t_fy] = wb; }
        __syncthreads();
    }
    // extraction: dead minima get death value from val slot
    for (int i = lane; i < (int)nm; i += 64) {
        if (par[i] != (u32)i)
            dval[k * NV + mlist[k * CAP + i]] = isb(val[i]);
    }
}

// ---------------- coordinate features -> bf16 directly into fused A ------------
__global__ void k_coordb(const float* __restrict__ f, const float* __restrict__ dval,
                         const float* __restrict__ tri_t, const float* __restrict__ gmu,
                         const float* __restrict__ gsig, const float* __restrict__ lw,
                         const float* __restrict__ rc, const float* __restrict__ rr,
                         u16* __restrict__ A) {
    int t = blockIdx.x * 256 + threadIdx.x;  // 160000
    int k = t / NV, v = t % NV;
    float b = f[t], d = dval[t];
    float o[12];
    float s = gsig[0];
    float inv2s2 = 1.0f / (2.0f * s * s);
    float r = fabsf(rr[0]);
#pragma unroll
    for (int j = 0; j < 3; j++) {
        float tri = d - fabsf(tri_t[j] - b);
        o[j] = tri > 0.f ? tri : 0.f;
        float dx = b - gmu[2 * j], dy = d - gmu[2 * j + 1];
        o[3 + j] = expf(-(dx * dx + dy * dy) * inv2s2);
        o[6 + j] = b * lw[2 * j] + d * lw[2 * j + 1];
        float q = fabsf(b - rc[2 * j]) + fabsf(d - rc[2 * j + 1]);
        o[9 + j] = 1.0f / (1.0f + q) - 1.0f / (1.0f + fabsf(r - q));
    }
    u16* dst = A + (size_t)v * KP + FIN + k * 12;  // 4B-aligned (2048+24k bytes)
    u32* d32 = (u32*)dst;
#pragma unroll
    for (int j = 0; j < 6; j++)
        d32[j] = (u32)f2bf(o[2 * j]) | ((u32)f2bf(o[2 * j + 1]) << 16);
}

// ---------------- GEMM2: out = A(bf16) @ W(bf16)^T + bias, MFMA ----------------
// Full-N blocks: grid 157, 512 threads (8 waves = 2M x 4N), wave tile 64x128.
// A is read EXACTLY once from HBM (each block owns 128 rows, all of N); W
// (1.2 MB) is L2-resident. Epilogue transposes 16x32 frag-pairs via per-wave
// LDS scratch so each store instruction writes 8 rows x 128 B FULL lines
// (float4/lane) -- kills the 8x partial-line write amplification seen in R5.
__global__ __launch_bounds__(512, 2) void k_gemm2(
    const u16* __restrict__ A, const u16* __restrict__ W,
    const float* __restrict__ bias, float* __restrict__ out) {
    __shared__ u16 As[128 * LDA];   // 18 KB
    __shared__ u16 Ws[512 * LDA];   // 72 KB (reused as f32 scratch in epilogue)
    int m0 = blockIdx.x * 128;
    int t = threadIdx.x;
    int wave = t >> 6, lane = t & 63;
    int wr = wave >> 2, wc = wave & 3;       // 2 x 4 wave grid
    int lrow = lane & 15, lq = lane >> 4;
    f32x4 acc[4][8];
#pragma unroll
    for (int mt = 0; mt < 4; mt++)
#pragma unroll
        for (int nt = 0; nt < 8; nt++) acc[mt][nt] = (f32x4){0.f, 0.f, 0.f, 0.f};

    int arow[2], acol[2], wrow[8], wcol[8];
    uint4 av[2], wv[8];
#pragma unroll
    for (int i = 0; i < 2; i++) {            // A chunk: 128x64 = 1024 uint4
        int c = i * 512 + t;
        arow[i] = c >> 3; acol[i] = (c & 7) * 8;
        av[i] = *(const uint4*)(A + (size_t)(m0 + arow[i]) * KP + acol[i]);
    }
#pragma unroll
    for (int i = 0; i < 8; i++) {            // W chunk: 512x64 = 4096 uint4
        int c = i * 512 + t;
        wrow[i] = c >> 3; wcol[i] = (c & 7) * 8;
        wv[i] = *(const uint4*)(W + (size_t)wrow[i] * KP + wcol[i]);
    }
#pragma unroll 1
    for (int step = 0; step < KP / 64; step++) {
        __syncthreads();
#pragma unroll
        for (int i = 0; i < 2; i++) *(uint4*)(As + arow[i] * LDA + acol[i]) = av[i];
#pragma unroll
        for (int i = 0; i < 8; i++) *(uint4*)(Ws + wrow[i] * LDA + wcol[i]) = wv[i];
        __syncthreads();
        int k0n = (step + 1 < KP / 64) ? (step + 1) * 64 : 0;  // prefetch (clamped)
#pragma unroll
        for (int i = 0; i < 2; i++)
            av[i] = *(const uint4*)(A + (size_t)(m0 + arow[i]) * KP + k0n + acol[i]);
#pragma unroll
        for (int i = 0; i < 8; i++)
            wv[i] = *(const uint4*)(W + (size_t)wrow[i] * KP + k0n + wcol[i]);
#pragma unroll
        for (int kh = 0; kh < 2; kh++) {
            int kk = kh * 32 + lq * 8;
            bf16x8 af[4], wf[8];
#pragma unroll
            for (int mt = 0; mt < 4; mt++)
                af[mt] = *(const bf16x8*)(As + (wr * 64 + mt * 16 + lrow) * LDA + kk);
#pragma unroll
            for (int nt = 0; nt < 8; nt++)
                wf[nt] = *(const bf16x8*)(Ws + (wc * 128 + nt * 16 + lrow) * LDA + kk);
#pragma unroll
            for (int mt = 0; mt < 4; mt++)
#pragma unroll
                for (int nt = 0; nt < 8; nt++)
                    acc[mt][nt] = __builtin_amdgcn_mfma_f32_16x16x32_bf16(
                        af[mt], wf[nt], acc[mt][nt], 0, 0, 0);
        }
    }
    // ---- epilogue: per-wave LDS transpose -> full-line float4 stores ----------
    __syncthreads();                          // all waves done reading Ws
    float* scr = (float*)Ws + wave * 576;     // 16 x 36 f32 per wave (18 KB total)
    int cg = lane & 7;                        // col group (4 floats)
    int rr8 = lane >> 3;                      // row within 8-row pass
#pragma unroll
    for (int np = 0; np < 4; np++) {          // frag-pairs: cols np*32..np*32+31
        int o = wc * 128 + np * 32 + cg * 4;
        f32x4 b4 = *(const f32x4*)(bias + o);
#pragma unroll
        for (int mt = 0; mt < 4; mt++) {
            // scatter frag-pair into scratch: row = lq*4+i, col = f*16+lrow
#pragma unroll
            for (int fh = 0; fh < 2; fh++) {
                f32x4 fr = acc[mt][2 * np + fh];
#pragma unroll
                for (int i = 0; i < 4; i++)
                    scr[(lq * 4 + i) * 36 + fh * 16 + lrow] = fr[i];
            }
            // gather row-major float4 and store full 128B lines (8 rows/instr)
#pragma unroll
            for (int p = 0; p < 2; p++) {
                int r = p * 8 + rr8;
                f32x4 vv = *(f32x4*)(scr + r * 36 + cg * 4);
                int v = m0 + wr * 64 + mt * 16 + r;
                if (v < NV) *(f32x4*)(out + (size_t)v * FOUT + o) = vv + b4;
            }
        }
    }
}

extern "C" void kernel_launch(void* const* d_in, const int* in_sizes, int n_in,
                              void* d_out, int out_size, void* d_ws, size_t ws_size,
                              hipStream_t stream) {
    const float* x     = (const float*)d_in[0];
    const int*   ei    = (const int*)d_in[1];
    const float* fw    = (const float*)d_in[2];
    const float* fbv   = (const float*)d_in[3];
    const float* tri_t = (const float*)d_in[4];
    const float* gmu   = (const float*)d_in[5];
    const float* gsig  = (const float*)d_in[6];
    const float* lw    = (const float*)d_in[7];
    const float* rc    = (const float*)d_in[8];
    const float* rr    = (const float*)d_in[9];
    const float* ow    = (const float*)d_in[10];
    const float* ob    = (const float*)d_in[11];
    float* out = (float*)d_out;

    char* p = (char*)d_ws;
    auto alloc = [&](size_t bytes) -> void* {
        void* q = (void*)p;
        p += (bytes + 255) & ~(size_t)255;
        return q;
    };
    float* f     = (float*)alloc((size_t)NK * NV * 4);
    u64*   cd    = (u64*)  alloc((size_t)NK * NV * 8);
    u32*   basin = (u32*)  alloc((size_t)NK * NV * 4);
    u32*   dense = (u32*)  alloc((size_t)NK * NV * 4);
    u32*   mlist = (u32*)  alloc((size_t)NK * CAP * 4);
    u32*   cnts  = (u32*)  alloc(64 * 4);
    u64*   wkey  = (u64*)  alloc((size_t)NK * NE * 8);
    u32*   ep    = (u32*)  alloc((size_t)NK * NE * 4);
    u32*   comp  = (u32*)  alloc((size_t)NK * CAP * 4);
    u64*   cand  = (u64*)  alloc((size_t)NK * CAP * 8);
    u64*   mkey  = (u64*)  alloc((size_t)NK * CAP * 8);
    float* dval  = (float*)alloc((size_t)NK * NV * 4);
    u16*   Ab    = (u16*)  alloc((size_t)MP * KP * 2);   // 46.3 MB fused [x|coord|pad]
    u16*   Wb    = (u16*)  alloc((size_t)FOUT * KP * 2); // 1.2 MB
    u32* nmin = cnts; u32* mstcnt = cnts + 8; u32* done = cnts + 16;

    k_init<<<128, 256, 0, stream>>>(comp, cand, cnts);
    k_fx<<<MP / 4, 256, 0, stream>>>(x, fw, fbv, f, Ab);
    k_castw<<<(FOUT * 144 + 255) / 256, 256, 0, stream>>>(ow, Wb);
    k_initdesc<<<625, 256, 0, stream>>>(f, cd, dval);
    k_descedge<<<3125, 256, 0, stream>>>(ei, f, cd);
    k_basmin<<<NK, 1024, 0, stream>>>(cd, basin, nmin, mlist, dense);
    k_edgeprep<<<3125, 256, 0, stream>>>(ei, f, basin, dense, wkey, ep);
    for (int r = 0; r < ROUNDS; r++) {
        k_candA<<<dim3(NB, NK), 256, 0, stream>>>(ep, wkey, comp, cand, done);
        k_round<<<NK, 1024, 0, stream>>>(cand, ep, comp, mstcnt, mkey, done);
    }
    k_sort<<<8, 1024, 0, stream>>>(mstcnt, mkey);
    k_pairw<<<8, 64, 0, stream>>>(nmin, mlist, mstcnt, mkey, ep, f, dval);
    k_coordb<<<625, 256, 0, stream>>>(f, dval, tri_t, gmu, gsig, lw, rc, rr, Ab);
    k_gemm2<<<157, 512, 0, stream>>>(Ab, Wb, ob, out);
}